// Round 1
// baseline (3227.818 us; speedup 1.0000x reference)
//
#include <hip/hip_runtime.h>
#include <math.h>

#define TID ((int)threadIdx.x)

namespace {
constexpr int NG = 16;     // G
constexpr int NB = 16;     // B
constexpr int NP_ = 2048;  // P
constexpr float EPSf = 1e-5f;

__device__ __forceinline__ unsigned fenc(float f){
  unsigned u = __float_as_uint(f);
  return (u & 0x80000000u) ? ~u : (u | 0x80000000u);
}
__device__ __forceinline__ float fdec(unsigned e){
  unsigned u = (e & 0x80000000u) ? (e & 0x7fffffffu) : ~e;
  return __uint_as_float(u);
}

// ---------------- FPS ----------------
// One block per cloud. 256 threads. Exact fp32 distance arithmetic
// (mul/add, no fma) to match numpy; first-index tie-break via packed u64 key.
template<int NPTS>
__global__ void __launch_bounds__(256) fps_kernel(const float* __restrict__ pts_all,
                                                  float* __restrict__ out_all, int npoint)
{
  constexpr int LP = NPTS / 256;
  const float* pts = pts_all + (size_t)blockIdx.x * NPTS * 3;
  float* out = out_all + (size_t)blockIdx.x * npoint * 3;
  float px[LP], py[LP], pz[LP], dmin[LP];
#pragma unroll
  for (int j = 0; j < LP; j++){
    int p = TID + 256 * j;
    px[j] = pts[p*3+0]; py[j] = pts[p*3+1]; pz[j] = pts[p*3+2];
    dmin[j] = 1e10f;
  }
  __shared__ unsigned long long red[4];
  int far = 0;
  for (int i = 0; i < npoint; i++){
    float cx = pts[far*3+0], cy = pts[far*3+1], cz = pts[far*3+2];
    if (TID == 0){ out[i*3+0]=cx; out[i*3+1]=cy; out[i*3+2]=cz; }
    unsigned long long bk = 0ull;
#pragma unroll
    for (int j = 0; j < LP; j++){
      float dx = __fsub_rn(px[j], cx);
      float dy = __fsub_rn(py[j], cy);
      float dz = __fsub_rn(pz[j], cz);
      float d  = __fadd_rn(__fadd_rn(__fmul_rn(dx,dx), __fmul_rn(dy,dy)), __fmul_rn(dz,dz));
      float dm = fminf(dmin[j], d);
      dmin[j] = dm;
      unsigned long long key = ((unsigned long long)__float_as_uint(dm) << 32)
                             | (unsigned)(0xFFFFFFFFu - (unsigned)(TID + 256*j));
      bk = bk > key ? bk : key;
    }
#pragma unroll
    for (int off = 32; off > 0; off >>= 1){
      unsigned long long ok = __shfl_xor(bk, off);
      bk = bk > ok ? bk : ok;
    }
    __syncthreads();                 // protect red[] from previous iteration's readers
    if ((TID & 63) == 0) red[TID >> 6] = bk;
    __syncthreads();
    unsigned long long m0 = red[0], m1 = red[1], m2 = red[2], m3 = red[3];
    m0 = m0 > m1 ? m0 : m1; m2 = m2 > m3 ? m2 : m3; m0 = m0 > m2 ? m0 : m2;
    far = (int)(0xFFFFFFFFu - (unsigned)(m0 & 0xFFFFFFFFull));
  }
}

// ---------------- generic small row-GEMM: out[row,c] = in[row,:K] . w[g,:,c] + b[g,c] ----------------
template<int C, int K>
__global__ void __launch_bounds__(256) rowgemm_kernel(const float* __restrict__ in,
    const float* __restrict__ w, const float* __restrict__ bias,
    float* __restrict__ out, int rows_per_g)
{
  constexpr int RPB = 256 / C;
  __shared__ float lin[RPB * K];
  size_t row0 = (size_t)blockIdx.x * RPB;
  for (int i = TID; i < RPB*K; i += 256) lin[i] = in[row0*K + i];
  __syncthreads();
  int r = TID / C, c = TID % C;
  size_t row = row0 + r;
  int g = (int)(row / rows_per_g);
  float acc = bias[(size_t)g*C + c];
  const float* wg = w + (size_t)g*K*C + c;
#pragma unroll
  for (int k = 0; k < K; k++) acc = fmaf(lin[r*K + k], wg[(size_t)k*C], acc);
  out[row*C + c] = acc;
}

// ---------------- 1024-wide GEMM (K=128): pointnet L3 (fused max+stats) / axform c3 ----------------
__global__ void __launch_bounds__(256) big1024_kernel(const float* __restrict__ in,
    const float* __restrict__ w, const float* __restrict__ bias,
    float* __restrict__ out, float* __restrict__ sum, float* __restrict__ sumsq,
    unsigned* __restrict__ maxenc, int rows_per_g, int stats_mode)
{
  __shared__ float lin[32 * 128];
  size_t row0 = (size_t)blockIdx.x * 32;
  int g = (int)(row0 / rows_per_g);
  for (int i = TID; i < 32*128; i += 256) lin[i] = in[row0*128 + i];
  __syncthreads();
  int c0 = blockIdx.y * 512 + TID, c1 = c0 + 256;
  float a0[32], a1[32];
  float b0 = bias[(size_t)g*1024 + c0], b1 = bias[(size_t)g*1024 + c1];
#pragma unroll
  for (int r = 0; r < 32; r++){ a0[r] = b0; a1[r] = b1; }
  const float* wg = w + (size_t)g*128*1024;
  for (int k = 0; k < 128; k++){
    float w0 = wg[(size_t)k*1024 + c0];
    float w1 = wg[(size_t)k*1024 + c1];
#pragma unroll
    for (int r = 0; r < 32; r++){
      float lv = lin[r*128 + k];
      a0[r] = fmaf(lv, w0, a0[r]);
      a1[r] = fmaf(lv, w1, a1[r]);
    }
  }
  if (!stats_mode){
#pragma unroll
    for (int r = 0; r < 32; r++){
      out[(row0 + r)*1024 + c0] = a0[r];
      out[(row0 + r)*1024 + c1] = a1[r];
    }
  } else {
    int b = (int)(row0 / 2048);
    float s0=0.f,q0=0.f,m0=-1e38f,s1=0.f,q1=0.f,m1=-1e38f;
#pragma unroll
    for (int r = 0; r < 32; r++){
      s0 += a0[r]; q0 = fmaf(a0[r], a0[r], q0); m0 = fmaxf(m0, a0[r]);
      s1 += a1[r]; q1 = fmaf(a1[r], a1[r], q1); m1 = fmaxf(m1, a1[r]);
    }
    atomicAdd(&sum[c0], s0);  atomicAdd(&sumsq[c0], q0);
    atomicAdd(&sum[c1], s1);  atomicAdd(&sumsq[c1], q1);
    atomicMax(&maxenc[(size_t)b*1024 + c0], fenc(m0));
    atomicMax(&maxenc[(size_t)b*1024 + c1], fenc(m1));
  }
}

// ---------------- skinny per-g GEMM: out[g,b,j] = in[g,b,:K] . w[g,:,j] + b[g,j] (b=0..15) ----------------
__global__ void mapgemm_kernel(const float* __restrict__ in, int in_gstride,
    const float* __restrict__ w, const float* __restrict__ bias,
    float* __restrict__ out, int K, int J)
{
  __shared__ float lin[16 * 128];
  int g = blockIdx.y;
  int j = blockIdx.x * blockDim.x + TID;
  const float* ing = in + (size_t)g * in_gstride;
  float acc[16];
  float bv = bias[(size_t)g*J + j];
#pragma unroll
  for (int b = 0; b < 16; b++) acc[b] = bv;
  for (int kt = 0; kt < K; kt += 128){
    for (int i = TID; i < 2048; i += blockDim.x){
      int b = i >> 7, k = i & 127;
      lin[i] = ing[(size_t)b*K + kt + k];
    }
    __syncthreads();
    const float* wg = w + ((size_t)g*K + kt)*J + j;
    for (int k = 0; k < 128; k++){
      float wv = wg[(size_t)k*J];
#pragma unroll
      for (int b = 0; b < 16; b++) acc[b] = fmaf(lin[b*128 + k], wv, acc[b]);
    }
    __syncthreads();
  }
  for (int b = 0; b < 16; b++) out[((size_t)g*16 + b)*J + j] = acc[b];
}

// ---------------- BN statistics: one block per (g,c); reduce R rows ----------------
__global__ void __launch_bounds__(256) stats_kernel(const float* __restrict__ in,
    float* __restrict__ stats, int R, int C)
{
  int gc = blockIdx.x;
  int g = gc / C, c = gc % C;
  const float* base = in + (size_t)g*R*C + c;
  float s = 0.f, q = 0.f;
  for (int r = TID; r < R; r += 256){ float v = base[(size_t)r*C]; s += v; q = fmaf(v, v, q); }
  __shared__ float ls[256], lq[256];
  ls[TID] = s; lq[TID] = q; __syncthreads();
  for (int off = 128; off > 0; off >>= 1){
    if (TID < off){ ls[TID] += ls[TID+off]; lq[TID] += lq[TID+off]; }
    __syncthreads();
  }
  if (TID == 0){
    float mean = ls[0] / (float)R;
    float var  = lq[0] / (float)R - mean*mean;
    stats[(size_t)gc*2]   = mean;
    stats[(size_t)gc*2+1] = rsqrtf(fmaxf(var, 0.f) + EPSf);
  }
}

__global__ void bnapply_kernel(float* __restrict__ io, const float* __restrict__ stats,
                               size_t total, int RC, int C, int relu)
{
  size_t i = (size_t)blockIdx.x*256 + TID;
  if (i >= total) return;
  int g = (int)(i / (size_t)RC);
  int c = (int)(i % (size_t)C);
  const float* st = stats + ((size_t)g*C + c)*2;
  float v = (io[i] - st[0]) * st[1];
  if (relu) v = fmaxf(v, 0.f);
  io[i] = v;
}

// feat[b,c] = (max_p h3[b,p,c] - mean_c) * rstd_c
__global__ void feat_kernel(const unsigned* __restrict__ me, const float* __restrict__ sum,
                            const float* __restrict__ sq, float* __restrict__ feat)
{
  int t = blockIdx.x*256 + TID;     // 16384 = B*1024
  int c = t & 1023;
  float mean = sum[c] * (1.f/32768.f);
  float var  = sq[c] * (1.f/32768.f) - mean*mean;
  float rs   = rsqrtf(fmaxf(var, 0.f) + EPSf);
  feat[t] = (fdec(me[t]) - mean) * rs;
}

// ---------------- fused softmax(over n) + y=w·xb + c4 ----------------
__global__ void __launch_bounds__(256) softmax_kernel(const float* __restrict__ h,
    const float* __restrict__ xb, const float* __restrict__ c4w, const float* __restrict__ c4b,
    float* __restrict__ out_pts, float* __restrict__ out_x1)
{
  int gb = blockIdx.x;
  int g = gb >> 4, b = gb & 15;
  __shared__ float xbl[4096];
  __shared__ float c4l[96];
  __shared__ float c4bl[3];
  for (int i = TID; i < 4096; i += 256) xbl[i] = xb[(size_t)gb*4096 + i];
  if (TID < 96) c4l[TID] = c4w[g*96 + TID];
  if (TID < 3)  c4bl[TID] = c4b[g*3 + TID];
  __syncthreads();
  const float* hb = h + (size_t)gb*128*1024;
  for (int e = TID; e < 1024; e += 256){
    float m = -1e38f;
    for (int n = 0; n < 128; n++) m = fmaxf(m, hb[(size_t)n*1024 + e]);
    float4 acc[8];
#pragma unroll
    for (int q = 0; q < 8; q++) acc[q] = make_float4(0.f,0.f,0.f,0.f);
    float s = 0.f;
    for (int n = 0; n < 128; n++){
      float wv = __expf(hb[(size_t)n*1024 + e] - m);
      s += wv;
      const float4* xr = (const float4*)(xbl + n*32);
#pragma unroll
      for (int q = 0; q < 8; q++){
        float4 xv = xr[q];
        acc[q].x = fmaf(wv, xv.x, acc[q].x);
        acc[q].y = fmaf(wv, xv.y, acc[q].y);
        acc[q].z = fmaf(wv, xv.z, acc[q].z);
        acc[q].w = fmaf(wv, xv.w, acc[q].w);
      }
    }
    float rs = 1.f / s;
    float o0 = 0.f, o1 = 0.f, o2 = 0.f;
#pragma unroll
    for (int q = 0; q < 8; q++){
      int k = q*4;
      o0 += acc[q].x*c4l[(k+0)*3+0] + acc[q].y*c4l[(k+1)*3+0] + acc[q].z*c4l[(k+2)*3+0] + acc[q].w*c4l[(k+3)*3+0];
      o1 += acc[q].x*c4l[(k+0)*3+1] + acc[q].y*c4l[(k+1)*3+1] + acc[q].z*c4l[(k+2)*3+1] + acc[q].w*c4l[(k+3)*3+1];
      o2 += acc[q].x*c4l[(k+0)*3+2] + acc[q].y*c4l[(k+1)*3+2] + acc[q].z*c4l[(k+2)*3+2] + acc[q].w*c4l[(k+3)*3+2];
    }
    o0 = fmaf(rs, o0, c4bl[0]);
    o1 = fmaf(rs, o1, c4bl[1]);
    o2 = fmaf(rs, o2, c4bl[2]);
    size_t po = ((size_t)gb*1024 + e)*3;
    out_pts[po+0] = o0; out_pts[po+1] = o1; out_pts[po+2] = o2;
    if (out_x1){
      size_t xo = (((size_t)b*16 + g)*1024 + e)*3;   // x_1[b, g*1024+e, c]
      out_x1[xo+0] = o0; out_x1[xo+1] = o1; out_x1[xo+2] = o2;
    }
  }
}

// ---------------- x_2 = concat(fps1, x_partial) + d2, laid out (b, g*1024+i, c) ----------------
__global__ void combine_kernel(const float* __restrict__ fps1, const float* __restrict__ xpart,
                               const float* __restrict__ d2, float* __restrict__ x2)
{
  size_t i = (size_t)blockIdx.x*256 + TID;
  if (i >= (size_t)NG*NB*1024*3) return;
  int c = (int)(i % 3);
  size_t t = i / 3;
  int e = (int)(t % 1024);
  size_t gb = t / 1024;
  int g = (int)(gb >> 4), b = (int)(gb & 15);
  float base;
  if (e < 512) base = fps1[(gb*512 + e)*3 + c];
  else         base = xpart[((size_t)b*512 + (e - 512))*3 + c];
  x2[(((size_t)b*16384) + (size_t)g*1024 + e)*3 + c] = base + d2[i];
}

} // anon namespace

extern "C" void kernel_launch(void* const* d_in, const int* in_sizes, int n_in,
                              void* d_out, int out_size, void* d_ws, size_t ws_size,
                              hipStream_t stream)
{
  (void)in_sizes; (void)n_in; (void)out_size; (void)ws_size;
  const float* x    = (const float*)d_in[0];
  const float* pnw1 = (const float*)d_in[1];
  const float* pnb1 = (const float*)d_in[2];
  const float* pnw2 = (const float*)d_in[3];
  const float* pnb2 = (const float*)d_in[4];
  const float* pnw3 = (const float*)d_in[5];
  const float* pnb3 = (const float*)d_in[6];
  const float* mpw[4] = {(const float*)d_in[7],(const float*)d_in[9],(const float*)d_in[11],(const float*)d_in[13]};
  const float* mpb[4] = {(const float*)d_in[8],(const float*)d_in[10],(const float*)d_in[12],(const float*)d_in[14]};

  float* ws = (float*)d_ws;
  float* x_partial = ws;                         // 24576
  float* feat      = ws + 24576;                 // 16384
  float* mfeat     = ws + 40960;                 // 32768
  float* stats     = ws + 73728;                 // 32768 generic (mean,rstd pairs)
  float* pnsum     = ws + 73728 + 32768;         // 1024
  float* pnsq      = pnsum + 1024;               // 1024
  unsigned* maxenc = (unsigned*)(pnsq + 1024);   // 16384 u32
  float* mapA      = ws + 139264;                // 262144
  float* mapB      = mapA + 262144;              // 262144
  float* xb        = mapB + 262144;              // 4194304
  float* c1o       = xb + 4194304;               // 2097152 (also pointnet h1)
  float* c2o       = c1o + 2097152;              // 4194304 (also pointnet h2)
  float* hbuf      = c2o + 4194304;              // 33554432
  float* x1g       = hbuf + 33554432;            // 786432
  float* d2buf     = x1g + 786432;               // 786432
  float* fps1b     = d2buf + 786432;             // 393216   (total ~188 MB)

  float* xout1 = (float*)d_out;
  float* xout2 = xout1 + 786432;

  // zero atomic accumulators (re-zeroed on every graph replay)
  hipMemsetAsync(pnsum, 0, (1024 + 1024 + 16384)*sizeof(float), stream);

  // FPS on input cloud
  fps_kernel<2048><<<16, 256, 0, stream>>>(x, x_partial, 512);

  // PointNet
  rowgemm_kernel<64,3><<<8192, 256, 0, stream>>>(x, pnw1, pnb1, c1o, 32768);
  stats_kernel<<<64, 256, 0, stream>>>(c1o, stats, 32768, 64);
  bnapply_kernel<<<8192, 256, 0, stream>>>(c1o, stats, 2097152, 2097152, 64, 1);
  rowgemm_kernel<128,64><<<16384, 256, 0, stream>>>(c1o, pnw2, pnb2, c2o, 32768);
  stats_kernel<<<128, 256, 0, stream>>>(c2o, stats, 32768, 128);
  bnapply_kernel<<<16384, 256, 0, stream>>>(c2o, stats, 4194304, 4194304, 128, 1);
  big1024_kernel<<<dim3(1024,2), 256, 0, stream>>>(c2o, pnw3, pnb3, nullptr, pnsum, pnsq, maxenc, 32768, 1);
  feat_kernel<<<64, 256, 0, stream>>>(maxenc, pnsum, pnsq, feat);

  // Mapping MLP (4 layers, per-branch weights)
  mapgemm_kernel<<<dim3(4,16), 256, 0, stream>>>(feat, 0,     mpw[0], mpb[0], mapA, 1024, 1024);
  stats_kernel<<<16384, 256, 0, stream>>>(mapA, stats, 16, 1024);
  bnapply_kernel<<<1024, 256, 0, stream>>>(mapA, stats, 262144, 16384, 1024, 1);
  mapgemm_kernel<<<dim3(4,16), 256, 0, stream>>>(mapA, 16384, mpw[1], mpb[1], mapB, 1024, 1024);
  stats_kernel<<<16384, 256, 0, stream>>>(mapB, stats, 16, 1024);
  bnapply_kernel<<<1024, 256, 0, stream>>>(mapB, stats, 262144, 16384, 1024, 1);
  mapgemm_kernel<<<dim3(4,16), 256, 0, stream>>>(mapB, 16384, mpw[2], mpb[2], mapA, 1024, 1024);
  stats_kernel<<<16384, 256, 0, stream>>>(mapA, stats, 16, 1024);
  bnapply_kernel<<<1024, 256, 0, stream>>>(mapA, stats, 262144, 16384, 1024, 1);
  mapgemm_kernel<<<dim3(1,16), 128, 0, stream>>>(mapA, 16384, mpw[3], mpb[3], mfeat, 1024, 128);
  stats_kernel<<<2048, 256, 0, stream>>>(mfeat, stats, 16, 128);
  bnapply_kernel<<<128, 256, 0, stream>>>(mfeat, stats, 32768, 2048, 128, 1);

  // Two AXform heads: p=0 -> generation (x1g, writes x_1), p=1 -> refinement (d2buf)
  for (int p = 0; p < 2; p++){
    const float* fw  = (const float*)d_in[15 + p*10 + 0];
    const float* fb  = (const float*)d_in[15 + p*10 + 1];
    const float* c1w = (const float*)d_in[15 + p*10 + 2];
    const float* c1b = (const float*)d_in[15 + p*10 + 3];
    const float* c2w = (const float*)d_in[15 + p*10 + 4];
    const float* c2b = (const float*)d_in[15 + p*10 + 5];
    const float* c3w = (const float*)d_in[15 + p*10 + 6];
    const float* c3b = (const float*)d_in[15 + p*10 + 7];
    const float* c4w = (const float*)d_in[15 + p*10 + 8];
    const float* c4b = (const float*)d_in[15 + p*10 + 9];

    mapgemm_kernel<<<dim3(16,16), 256, 0, stream>>>(mfeat, 2048, fw, fb, xb, 128, 4096);
    rowgemm_kernel<64,32><<<8192, 256, 0, stream>>>(xb, c1w, c1b, c1o, 2048);
    stats_kernel<<<1024, 256, 0, stream>>>(c1o, stats, 2048, 64);
    bnapply_kernel<<<8192, 256, 0, stream>>>(c1o, stats, 2097152, 131072, 64, 1);
    rowgemm_kernel<128,64><<<16384, 256, 0, stream>>>(c1o, c2w, c2b, c2o, 2048);
    stats_kernel<<<2048, 256, 0, stream>>>(c2o, stats, 2048, 128);
    bnapply_kernel<<<16384, 256, 0, stream>>>(c2o, stats, 4194304, 262144, 128, 1);
    big1024_kernel<<<dim3(1024,2), 256, 0, stream>>>(c2o, c3w, c3b, hbuf, nullptr, nullptr, nullptr, 2048, 0);
    softmax_kernel<<<256, 256, 0, stream>>>(hbuf, xb, c4w, c4b,
                                            p == 0 ? x1g : d2buf,
                                            p == 0 ? xout1 : nullptr);
  }

  // FPS on each generated cloud, then combine into x_2
  fps_kernel<1024><<<256, 256, 0, stream>>>(x1g, fps1b, 512);
  combine_kernel<<<3072, 256, 0, stream>>>(fps1b, x_partial, d2buf, xout2);
}

// Round 3
// 2514.509 us; speedup vs baseline: 1.2837x; 1.2837x over previous
//
#include <hip/hip_runtime.h>
#include <math.h>

#define TID ((int)threadIdx.x)

namespace {
constexpr float EPSf = 1e-5f;

struct FpsArgs {
  const float* pts; float* out; float* dmin; int* far;
  int it0, it1, nc;
};

__device__ __forceinline__ unsigned fenc(float f){
  unsigned u = __float_as_uint(f);
  return (u & 0x80000000u) ? ~u : (u | 0x80000000u);
}
__device__ __forceinline__ float fdec(unsigned e){
  unsigned u = (e & 0x80000000u) ? (e & 0x7fffffffu) : ~e;
  return __uint_as_float(u);
}

// DPP combine step for (max dist, min index on tie) wave-64 reduction.
template<int CTRL>
__device__ __forceinline__ void dpp_comb(float& bm, int& bp){
  int om_i = __builtin_amdgcn_update_dpp(__float_as_int(bm), __float_as_int(bm), CTRL, 0xf, 0xf, false);
  int op   = __builtin_amdgcn_update_dpp(bp, bp, CTRL, 0xf, 0xf, false);
  float om = __int_as_float(om_i);
  if (om > bm || (om == bm && op < bp)){ bm = om; bp = op; }
}

// ---------------- FPS body (runs as sidecar blocks inside other kernels) ----
// 256 threads per cloud, LP points per thread (NPTS = 256*LP). Exact fp32
// (mul/add, no fma) to match numpy; max-dist / min-index tie-break.
// Checkpointable: [it0, it1) chunk; state = dmin[] + far.
template<int LP>
__device__ void fps_body(const FpsArgs& a, int ci){
  const int NPTS = 256*LP;
  const float* pts = a.pts + (size_t)ci * NPTS * 3;
  float* out = a.out + (size_t)ci * 512 * 3;
  float* dst = a.dmin + (size_t)ci * NPTS;
  float px[LP], py[LP], pz[LP], dmin[LP];
#pragma unroll
  for (int j = 0; j < LP; j++){
    int p = TID + 256*j;
    px[j] = pts[p*3+0]; py[j] = pts[p*3+1]; pz[j] = pts[p*3+2];
  }
  int far;
  if (a.it0 == 0){
#pragma unroll
    for (int j = 0; j < LP; j++) dmin[j] = 1e10f;
    far = 0;
  } else {
#pragma unroll
    for (int j = 0; j < LP; j++) dmin[j] = dst[TID + 256*j];
    far = a.far[ci];
  }
  __shared__ unsigned long long red2[2][4];
  for (int i = a.it0; i < a.it1; i++){
    float cx = pts[far*3+0], cy = pts[far*3+1], cz = pts[far*3+2];
    if (TID == 0){ out[i*3+0]=cx; out[i*3+1]=cy; out[i*3+2]=cz; }
    float bm = -1.f; int bp = 0;
#pragma unroll
    for (int j = 0; j < LP; j++){
      float dx = __fsub_rn(px[j], cx);
      float dy = __fsub_rn(py[j], cy);
      float dz = __fsub_rn(pz[j], cz);
      float d  = __fadd_rn(__fadd_rn(__fmul_rn(dx,dx), __fmul_rn(dy,dy)), __fmul_rn(dz,dz));
      float dm = fminf(dmin[j], d);
      dmin[j] = dm;
      if (dm > bm){ bm = dm; bp = TID + 256*j; }
    }
    // wave64 reduce via DPP (VALU, no DS ops)
    dpp_comb<0x111>(bm,bp); dpp_comb<0x112>(bm,bp); dpp_comb<0x114>(bm,bp);
    dpp_comb<0x118>(bm,bp); dpp_comb<0x142>(bm,bp); dpp_comb<0x143>(bm,bp);
    unsigned long long key =
      ((unsigned long long)(unsigned)__builtin_amdgcn_readlane(__float_as_int(bm), 63) << 32)
      | (unsigned)~(unsigned)__builtin_amdgcn_readlane(bp, 63);
    if ((TID & 63) == 63) red2[i&1][TID>>6] = key;
    __syncthreads();
    unsigned long long k0=red2[i&1][0], k1=red2[i&1][1], k2=red2[i&1][2], k3=red2[i&1][3];
    k0 = k0>k1?k0:k1; k2 = k2>k3?k2:k3; k0 = k0>k2?k0:k2;
    far = (int)~(unsigned)k0;
  }
  if (a.it1 < 512){
#pragma unroll
    for (int j = 0; j < LP; j++) dst[TID + 256*j] = dmin[j];
    if (TID == 0) a.far[ci] = far;
  }
}

// ---------------- small row-GEMM with optional BN(+relu) on input load -----
template<int C, int K, int FLP>
__global__ void __launch_bounds__(256) rowgemm_kernel(const float* __restrict__ in,
    const float* __restrict__ w, const float* __restrict__ bias, const float2* __restrict__ st2,
    float* __restrict__ out, int rows_per_g, FpsArgs fa)
{
  int bid = blockIdx.x;
  if constexpr (FLP > 0){
    if (bid < fa.nc){ fps_body<FLP>(fa, bid); return; }
    bid -= fa.nc;
  }
  constexpr int RPB = 256 / C;
  __shared__ float lin[RPB * K];
  size_t row0 = (size_t)bid * RPB;
  int g = (int)(row0 / rows_per_g);
  for (int i = TID; i < RPB*K; i += 256){
    float v = in[row0*(size_t)K + i];
    if (st2){ float2 s = st2[(size_t)g*K + (i % K)]; v = fmaxf((v - s.x)*s.y, 0.f); }
    lin[i] = v;
  }
  __syncthreads();
  int r = TID / C, c = TID % C;
  float acc = bias[(size_t)g*C + c];
  const float* wg = w + (size_t)g*K*C + c;
#pragma unroll
  for (int k = 0; k < K; k++) acc = fmaf(lin[r*K + k], wg[(size_t)k*C], acc);
  out[(row0 + r)*C + c] = acc;
}

// ---------------- 1024-wide GEMM (K=128), optional input BN, optional stats
template<int FLP>
__global__ void __launch_bounds__(256) big1024_kernel(const float* __restrict__ in,
    const float* __restrict__ w, const float* __restrict__ bias, const float2* __restrict__ st2,
    float* __restrict__ out, float* __restrict__ ps, float* __restrict__ pq,
    unsigned* __restrict__ maxenc, int rows_per_g, int stats_mode, FpsArgs fa)
{
  int bid = blockIdx.x;
  if constexpr (FLP > 0){
    if (bid < fa.nc){ fps_body<FLP>(fa, bid); return; }
    bid -= fa.nc;
  }
  int rb = bid >> 1, ch = bid & 1;
  __shared__ float lin[32 * 128];
  size_t row0 = (size_t)rb * 32;
  int g = (int)(row0 / rows_per_g);
  for (int i = TID; i < 32*128; i += 256){
    float v = in[row0*128 + i];
    if (st2){ float2 s = st2[(size_t)g*128 + (i & 127)]; v = fmaxf((v - s.x)*s.y, 0.f); }
    lin[i] = v;
  }
  __syncthreads();
  int c0 = ch*512 + TID, c1 = c0 + 256;
  float a0[32], a1[32];
  float b0 = bias[(size_t)g*1024 + c0], b1 = bias[(size_t)g*1024 + c1];
#pragma unroll
  for (int r = 0; r < 32; r++){ a0[r] = b0; a1[r] = b1; }
  const float* wg = w + (size_t)g*128*1024;
  for (int k = 0; k < 128; k++){
    float w0 = wg[(size_t)k*1024 + c0];
    float w1 = wg[(size_t)k*1024 + c1];
#pragma unroll
    for (int r = 0; r < 32; r++){
      float lv = lin[r*128 + k];
      a0[r] = fmaf(lv, w0, a0[r]);
      a1[r] = fmaf(lv, w1, a1[r]);
    }
  }
  if (!stats_mode){
#pragma unroll
    for (int r = 0; r < 32; r++){
      out[(row0 + r)*1024 + c0] = a0[r];
      out[(row0 + r)*1024 + c1] = a1[r];
    }
  } else {
    int b = (int)(row0 / 2048);
    float s0=0.f,q0=0.f,m0=-1e38f,s1=0.f,q1=0.f,m1=-1e38f;
#pragma unroll
    for (int r = 0; r < 32; r++){
      s0 += a0[r]; q0 = fmaf(a0[r],a0[r],q0); m0 = fmaxf(m0, a0[r]);
      s1 += a1[r]; q1 = fmaf(a1[r],a1[r],q1); m1 = fmaxf(m1, a1[r]);
    }
    ps[(size_t)rb*1024 + c0] = s0; pq[(size_t)rb*1024 + c0] = q0;
    ps[(size_t)rb*1024 + c1] = s1; pq[(size_t)rb*1024 + c1] = q1;
    atomicMax(&maxenc[(size_t)b*1024 + c0], fenc(m0));
    atomicMax(&maxenc[(size_t)b*1024 + c1], fenc(m1));
  }
}

// ---------------- per-branch skinny GEMM, K-split partials, input BN -------
template<int FLP>
__global__ void __launch_bounds__(256) mapgemm_kernel(const float* __restrict__ in, int in_gstride,
    const float* __restrict__ w, const float* __restrict__ bias, const float2* __restrict__ st2,
    float* __restrict__ out, int K, int J, int JB, int NS, FpsArgs fa)
{
  int bid = blockIdx.x;
  if constexpr (FLP > 0){
    if (bid < fa.nc){ fps_body<FLP>(fa, bid); return; }
    bid -= fa.nc;
  }
  int kc = bid / (JB*16);
  int g  = (bid / JB) % 16;
  int jb = bid % JB;
  int j  = jb*256 + TID;
  bool jv = j < J;
  int jc = jv ? j : 0;
  int kchunk = K / NS;
  int k0 = kc * kchunk;
  __shared__ float lin[16 * 128];
  const float* ing = in + (size_t)g * in_gstride;
  float acc[16];
  float bv = (NS == 1 && jv) ? bias[(size_t)g*J + jc] : 0.f;
#pragma unroll
  for (int b = 0; b < 16; b++) acc[b] = bv;
  for (int kt = k0; kt < k0 + kchunk; kt += 128){
    __syncthreads();
    for (int i = TID; i < 2048; i += 256){
      int b = i >> 7, k = i & 127;
      float v = ing[(size_t)b*K + kt + k];
      if (st2){ float2 s = st2[(size_t)g*K + kt + k]; v = fmaxf((v - s.x)*s.y, 0.f); }
      lin[i] = v;
    }
    __syncthreads();
    const float* wg = w + ((size_t)g*K + kt)*J + jc;
    for (int k = 0; k < 128; k++){
      float wv = wg[(size_t)k*J];
#pragma unroll
      for (int b = 0; b < 16; b++) acc[b] = fmaf(lin[b*128 + k], wv, acc[b]);
    }
  }
  if (jv){
    if (NS == 1){
      for (int b = 0; b < 16; b++) out[((size_t)g*16 + b)*J + j] = acc[b];
    } else {
      for (int b = 0; b < 16; b++) out[(((size_t)kc*16 + g)*16 + b)*J + j] = acc[b];
    }
  }
}

// sum K-split partials + bias, write tensor, compute BN stats over B=16 -----
__global__ void __launch_bounds__(256) redstats_kernel(const float* __restrict__ part,
    const float* __restrict__ bias, float* __restrict__ out, float2* __restrict__ st2,
    int J, int NS)
{
  int t = blockIdx.x*256 + TID;   // over G*J
  int g = t / J, j = t % J;
  float bv = bias[t];
  float s = 0.f, q = 0.f;
  for (int b = 0; b < 16; b++){
    float v = bv;
    for (int c = 0; c < NS; c++) v += part[(((size_t)c*16 + g)*16 + b)*J + j];
    out[((size_t)g*16 + b)*J + j] = v;
    s += v; q = fmaf(v, v, q);
  }
  float mean = s * (1.f/16.f);
  float var  = q * (1.f/16.f) - mean*mean;
  st2[t] = make_float2(mean, rsqrtf(fmaxf(var, 0.f) + EPSf));
}

// chunked coalesced BN partial sums (deterministic; no atomics) -------------
__global__ void __launch_bounds__(256) statsacc_kernel(const float* __restrict__ in,
    float* __restrict__ part, int C, size_t chunk)
{
  size_t base = (size_t)blockIdx.x * chunk;
  int c = TID % C;
  float s = 0.f, q = 0.f;
  for (size_t idx = base + TID; idx < base + chunk; idx += 256){
    float v = in[idx]; s += v; q = fmaf(v, v, q);
  }
  __shared__ float ls[256], lq[256];
  ls[TID] = s; lq[TID] = q; __syncthreads();
  if (TID < C){
    for (int t = TID + C; t < 256; t += C){ s += ls[t]; q += lq[t]; }
    part[((size_t)blockIdx.x*C + c)*2]   = s;
    part[((size_t)blockIdx.x*C + c)*2+1] = q;
  }
}

__global__ void statsfin_kernel(const float* __restrict__ part, float2* __restrict__ st2,
    int C, int G, float invR)
{
  int slot = blockIdx.x*256 + TID;
  if (slot >= G*C) return;
  int g = slot / C, c = slot % C;
  int bpg = 256 / G;
  float s = 0.f, q = 0.f;
  for (int b = 0; b < bpg; b++){
    size_t p = ((size_t)(g*bpg + b)*C + c)*2;
    s += part[p]; q += part[p+1];
  }
  float mean = s*invR;
  float var  = q*invR - mean*mean;
  st2[slot] = make_float2(mean, rsqrtf(fmaxf(var, 0.f) + EPSf));
}

// PointNet L3: reduce per-rowblock partials -> per-channel (mean,rstd) ------
__global__ void pnfin_kernel(const float* __restrict__ ps, const float* __restrict__ pq,
                             float2* __restrict__ st)
{
  int c = blockIdx.x*256 + TID;   // 1024
  float s = 0.f, q = 0.f;
  for (int rb = 0; rb < 1024; rb++){ s += ps[rb*1024 + c]; q += pq[rb*1024 + c]; }
  float mean = s * (1.f/32768.f);
  float var  = q * (1.f/32768.f) - mean*mean;
  st[c] = make_float2(mean, rsqrtf(fmaxf(var, 0.f) + EPSf));
}

__global__ void feat_kernel(const unsigned* __restrict__ me, const float2* __restrict__ st,
                            float* __restrict__ feat)
{
  int t = blockIdx.x*256 + TID;   // 16384
  int c = t & 1023;
  float2 s = st[c];
  feat[t] = (fdec(me[t]) - s.x) * s.y;
}

// ---------------- fused softmax(over n) + y=w.xb + c4 ----------------------
template<int FLP>
__global__ void __launch_bounds__(256) softmax_kernel(const float* __restrict__ h,
    const float* __restrict__ xb, const float* __restrict__ c4w, const float* __restrict__ c4b,
    float* __restrict__ out_pts, float* __restrict__ out_x1, FpsArgs fa)
{
  int bid = blockIdx.x;
  if constexpr (FLP > 0){
    if (bid < fa.nc){ fps_body<FLP>(fa, bid); return; }
    bid -= fa.nc;
  }
  int gb = bid;
  int g = gb >> 4, b = gb & 15;
  __shared__ float xbl[4096];
  __shared__ float c4l[96];
  __shared__ float c4bl[3];
  for (int i = TID; i < 4096; i += 256) xbl[i] = xb[(size_t)gb*4096 + i];
  if (TID < 96) c4l[TID] = c4w[g*96 + TID];
  if (TID < 3)  c4bl[TID] = c4b[g*3 + TID];
  __syncthreads();
  const float* hb = h + (size_t)gb*128*1024;
  for (int e = TID; e < 1024; e += 256){
    float m = -1e38f;
    for (int n = 0; n < 128; n++) m = fmaxf(m, hb[(size_t)n*1024 + e]);
    float4 acc[8];
#pragma unroll
    for (int q = 0; q < 8; q++) acc[q] = make_float4(0.f,0.f,0.f,0.f);
    float s = 0.f;
    for (int n = 0; n < 128; n++){
      float wv = __expf(hb[(size_t)n*1024 + e] - m);
      s += wv;
      const float4* xr = (const float4*)(xbl + n*32);
#pragma unroll
      for (int q = 0; q < 8; q++){
        float4 xv = xr[q];
        acc[q].x = fmaf(wv, xv.x, acc[q].x);
        acc[q].y = fmaf(wv, xv.y, acc[q].y);
        acc[q].z = fmaf(wv, xv.z, acc[q].z);
        acc[q].w = fmaf(wv, xv.w, acc[q].w);
      }
    }
    float rs = 1.f / s;
    float o0 = 0.f, o1 = 0.f, o2 = 0.f;
#pragma unroll
    for (int q = 0; q < 8; q++){
      int k = q*4;
      o0 += acc[q].x*c4l[(k+0)*3+0] + acc[q].y*c4l[(k+1)*3+0] + acc[q].z*c4l[(k+2)*3+0] + acc[q].w*c4l[(k+3)*3+0];
      o1 += acc[q].x*c4l[(k+0)*3+1] + acc[q].y*c4l[(k+1)*3+1] + acc[q].z*c4l[(k+2)*3+1] + acc[q].w*c4l[(k+3)*3+1];
      o2 += acc[q].x*c4l[(k+0)*3+2] + acc[q].y*c4l[(k+1)*3+2] + acc[q].z*c4l[(k+2)*3+2] + acc[q].w*c4l[(k+3)*3+2];
    }
    o0 = fmaf(rs, o0, c4bl[0]);
    o1 = fmaf(rs, o1, c4bl[1]);
    o2 = fmaf(rs, o2, c4bl[2]);
    size_t po = ((size_t)gb*1024 + e)*3;
    out_pts[po+0] = o0; out_pts[po+1] = o1; out_pts[po+2] = o2;
    if (out_x1){
      size_t xo = (((size_t)b*16 + g)*1024 + e)*3;
      out_x1[xo+0] = o0; out_x1[xo+1] = o1; out_x1[xo+2] = o2;
    }
  }
}

// ---------------- x_2 = concat(fps1, x_partial) + d2 -----------------------
__global__ void combine_kernel(const float* __restrict__ fps1, const float* __restrict__ xpart,
                               const float* __restrict__ d2, float* __restrict__ x2)
{
  size_t i = (size_t)blockIdx.x*256 + TID;
  if (i >= (size_t)16*16*1024*3) return;
  int c = (int)(i % 3);
  size_t t = i / 3;
  int e = (int)(t % 1024);
  size_t gb = t / 1024;
  int g = (int)(gb >> 4), b = (int)(gb & 15);
  float base;
  if (e < 512) base = fps1[(gb*512 + e)*3 + c];
  else         base = xpart[((size_t)b*512 + (e - 512))*3 + c];
  x2[(((size_t)b*16384) + (size_t)g*1024 + e)*3 + c] = base + d2[i];
}

} // anon namespace

extern "C" void kernel_launch(void* const* d_in, const int* in_sizes, int n_in,
                              void* d_out, int out_size, void* d_ws, size_t ws_size,
                              hipStream_t stream)
{
  (void)in_sizes; (void)n_in; (void)out_size; (void)ws_size;
  const float* x    = (const float*)d_in[0];
  const float* pnw1 = (const float*)d_in[1];
  const float* pnb1 = (const float*)d_in[2];
  const float* pnw2 = (const float*)d_in[3];
  const float* pnb2 = (const float*)d_in[4];
  const float* pnw3 = (const float*)d_in[5];
  const float* pnb3 = (const float*)d_in[6];
  const float* mpw[4] = {(const float*)d_in[7],(const float*)d_in[9],(const float*)d_in[11],(const float*)d_in[13]};
  const float* mpb[4] = {(const float*)d_in[8],(const float*)d_in[10],(const float*)d_in[12],(const float*)d_in[14]};

  float* ws = (float*)d_ws;
  size_t o = 0;
  auto alloc = [&](size_t n){ float* p = ws + o; o += n; return p; };
  float* x_partial = alloc(24576);
  float* feat      = alloc(16384);
  float* mfeat     = alloc(32768);
  float2* st_pn1   = (float2*)alloc(128);
  float2* st_pn2   = (float2*)alloc(256);
  float2* st_pn3   = (float2*)alloc(2048);
  float2* st_c1    = (float2*)alloc(2048);
  float2* st_c2    = (float2*)alloc(4096);
  float2* st_map0  = (float2*)alloc(32768);
  float2* st_map1  = (float2*)alloc(32768);
  float2* st_map2  = (float2*)alloc(32768);
  float2* st_map3  = (float2*)alloc(4096);
  float* sa_part   = alloc(65536);
  float* pn_ps     = alloc(1048576);
  float* pn_pq     = alloc(1048576);
  unsigned* maxenc = (unsigned*)alloc(16384);
  float* mapA      = alloc(262144);
  float* mapB      = alloc(262144);
  float* mpart     = alloc(1048576);
  float* xb        = alloc(1048576);
  float* c1o       = alloc(2097152);
  float* c2o       = alloc(4194304);
  float* hbuf      = alloc(33554432);
  float* x1g       = alloc(786432);
  float* d2buf     = alloc(786432);
  float* fps1b     = alloc(393216);
  float* fpsA_dmin = alloc(32768);
  int*   fpsA_far  = (int*)alloc(16);
  float* fpsB_dmin = alloc(262144);
  int*   fpsB_far  = (int*)alloc(256);

  float* xout1 = (float*)d_out;
  float* xout2 = xout1 + 786432;

  hipMemsetAsync(maxenc, 0, 16384*sizeof(unsigned), stream);

  FpsArgs f0{};   // dummy for non-sidecar instantiations
  FpsArgs fa{x, x_partial, fpsA_dmin, fpsA_far, 0, 96, 16};

  // ---- PointNet (fps(x) rides as sidecar) ----
  rowgemm_kernel<64,3,8><<<8192+16, 256, 0, stream>>>(x, pnw1, pnb1, nullptr, c1o, 32768, fa);
  statsacc_kernel<<<256, 256, 0, stream>>>(c1o, sa_part, 64, 8192);
  statsfin_kernel<<<1, 256, 0, stream>>>(sa_part, st_pn1, 64, 1, 1.f/32768.f);
  fa.it0 = 96; fa.it1 = 256;
  rowgemm_kernel<128,64,8><<<16384+16, 256, 0, stream>>>(c1o, pnw2, pnb2, st_pn1, c2o, 32768, fa);
  statsacc_kernel<<<256, 256, 0, stream>>>(c2o, sa_part, 128, 16384);
  statsfin_kernel<<<1, 256, 0, stream>>>(sa_part, st_pn2, 128, 1, 1.f/32768.f);
  fa.it0 = 256; fa.it1 = 512;
  big1024_kernel<8><<<2048+16, 256, 0, stream>>>(c2o, pnw3, pnb3, st_pn2, nullptr,
                                                 pn_ps, pn_pq, maxenc, 32768, 1, fa);
  pnfin_kernel<<<4, 256, 0, stream>>>(pn_ps, pn_pq, st_pn3);
  feat_kernel<<<64, 256, 0, stream>>>(maxenc, st_pn3, feat);

  // ---- Mapping MLP (K-split x4, deterministic reduce + stats) ----
  mapgemm_kernel<0><<<256, 256, 0, stream>>>(feat, 0,     mpw[0], nullptr, nullptr, mpart, 1024, 1024, 4, 4, f0);
  redstats_kernel<<<64, 256, 0, stream>>>(mpart, mpb[0], mapA, st_map0, 1024, 4);
  mapgemm_kernel<0><<<256, 256, 0, stream>>>(mapA, 16384, mpw[1], nullptr, st_map0, mpart, 1024, 1024, 4, 4, f0);
  redstats_kernel<<<64, 256, 0, stream>>>(mpart, mpb[1], mapB, st_map1, 1024, 4);
  mapgemm_kernel<0><<<256, 256, 0, stream>>>(mapB, 16384, mpw[2], nullptr, st_map1, mpart, 1024, 1024, 4, 4, f0);
  redstats_kernel<<<64, 256, 0, stream>>>(mpart, mpb[2], mapA, st_map2, 1024, 4);
  mapgemm_kernel<0><<<64, 256, 0, stream>>>(mapA, 16384, mpw[3], nullptr, st_map2, mpart, 1024, 128, 1, 4, f0);
  redstats_kernel<<<8, 256, 0, stream>>>(mpart, mpb[3], mfeat, st_map3, 128, 4);

  // ---- Two AXform heads; fps(x1g) rides head 1 ----
  for (int p = 0; p < 2; p++){
    const float* fw  = (const float*)d_in[15 + p*10 + 0];
    const float* fb  = (const float*)d_in[15 + p*10 + 1];
    const float* c1w = (const float*)d_in[15 + p*10 + 2];
    const float* c1b = (const float*)d_in[15 + p*10 + 3];
    const float* c2w = (const float*)d_in[15 + p*10 + 4];
    const float* c2b = (const float*)d_in[15 + p*10 + 5];
    const float* c3w = (const float*)d_in[15 + p*10 + 6];
    const float* c3b = (const float*)d_in[15 + p*10 + 7];
    const float* c4w = (const float*)d_in[15 + p*10 + 8];
    const float* c4b = (const float*)d_in[15 + p*10 + 9];

    if (p == 0){
      mapgemm_kernel<0><<<256, 256, 0, stream>>>(mfeat, 2048, fw, fb, st_map3, xb, 128, 4096, 16, 1, f0);
      rowgemm_kernel<64,32,0><<<8192, 256, 0, stream>>>(xb, c1w, c1b, nullptr, c1o, 2048, f0);
      statsacc_kernel<<<256, 256, 0, stream>>>(c1o, sa_part, 64, 8192);
      statsfin_kernel<<<4, 256, 0, stream>>>(sa_part, st_c1, 64, 16, 1.f/2048.f);
      rowgemm_kernel<128,64,0><<<16384, 256, 0, stream>>>(c1o, c2w, c2b, st_c1, c2o, 2048, f0);
      statsacc_kernel<<<256, 256, 0, stream>>>(c2o, sa_part, 128, 16384);
      statsfin_kernel<<<8, 256, 0, stream>>>(sa_part, st_c2, 128, 16, 1.f/2048.f);
      big1024_kernel<0><<<2048, 256, 0, stream>>>(c2o, c3w, c3b, st_c2, hbuf,
                                                  nullptr, nullptr, nullptr, 2048, 0, f0);
      softmax_kernel<0><<<256, 256, 0, stream>>>(hbuf, xb, c4w, c4b, x1g, xout1, f0);
    } else {
      FpsArgs fb_{x1g, fps1b, fpsB_dmin, fpsB_far, 0, 64, 256};
      mapgemm_kernel<4><<<256+256, 256, 0, stream>>>(mfeat, 2048, fw, fb, st_map3, xb, 128, 4096, 16, 1, fb_);
      fb_.it0 = 64; fb_.it1 = 128;
      rowgemm_kernel<64,32,4><<<8192+256, 256, 0, stream>>>(xb, c1w, c1b, nullptr, c1o, 2048, fb_);
      statsacc_kernel<<<256, 256, 0, stream>>>(c1o, sa_part, 64, 8192);
      statsfin_kernel<<<4, 256, 0, stream>>>(sa_part, st_c1, 64, 16, 1.f/2048.f);
      fb_.it0 = 128; fb_.it1 = 256;
      rowgemm_kernel<128,64,4><<<16384+256, 256, 0, stream>>>(c1o, c2w, c2b, st_c1, c2o, 2048, fb_);
      statsacc_kernel<<<256, 256, 0, stream>>>(c2o, sa_part, 128, 16384);
      statsfin_kernel<<<8, 256, 0, stream>>>(sa_part, st_c2, 128, 16, 1.f/2048.f);
      fb_.it0 = 256; fb_.it1 = 448;
      big1024_kernel<4><<<2048+256, 256, 0, stream>>>(c2o, c3w, c3b, st_c2, hbuf,
                                                      nullptr, nullptr, nullptr, 2048, 0, fb_);
      fb_.it0 = 448; fb_.it1 = 512;
      softmax_kernel<4><<<256+256, 256, 0, stream>>>(hbuf, xb, c4w, c4b, d2buf, nullptr, fb_);
    }
  }

  combine_kernel<<<3072, 256, 0, stream>>>(fps1b, x_partial, d2buf, xout2);
}

// Round 4
// 2103.290 us; speedup vs baseline: 1.5347x; 1.1955x over previous
//
#include <hip/hip_runtime.h>
#include <math.h>

#define TID ((int)threadIdx.x)

namespace {
constexpr float EPSf = 1e-5f;

struct FpsArgs {
  const float* pts; float* out; float* dmin; int* far;
  int it0, it1, nc;
};

__device__ __forceinline__ unsigned fenc(float f){
  unsigned u = __float_as_uint(f);
  return (u & 0x80000000u) ? ~u : (u | 0x80000000u);
}
__device__ __forceinline__ float fdec(unsigned e){
  unsigned u = (e & 0x80000000u) ? (e & 0x7fffffffu) : ~e;
  return __uint_as_float(u);
}

// DPP combine step for (max dist, min index on tie) wave-64 reduction.
template<int CTRL>
__device__ __forceinline__ void dpp_comb(float& bm, int& bp){
  int om_i = __builtin_amdgcn_update_dpp(__float_as_int(bm), __float_as_int(bm), CTRL, 0xf, 0xf, false);
  int op   = __builtin_amdgcn_update_dpp(bp, bp, CTRL, 0xf, 0xf, false);
  float om = __int_as_float(om_i);
  if (om > bm || (om == bm && op < bp)){ bm = om; bp = op; }
}

// ---------------- FPS body (runs as sidecar blocks inside other kernels) ----
template<int LP>
__device__ void fps_body(const FpsArgs& a, int ci){
  const int NPTS = 256*LP;
  const float* pts = a.pts + (size_t)ci * NPTS * 3;
  float* out = a.out + (size_t)ci * 512 * 3;
  float* dst = a.dmin + (size_t)ci * NPTS;
  float px[LP], py[LP], pz[LP], dmin[LP];
#pragma unroll
  for (int j = 0; j < LP; j++){
    int p = TID + 256*j;
    px[j] = pts[p*3+0]; py[j] = pts[p*3+1]; pz[j] = pts[p*3+2];
  }
  int far;
  if (a.it0 == 0){
#pragma unroll
    for (int j = 0; j < LP; j++) dmin[j] = 1e10f;
    far = 0;
  } else {
#pragma unroll
    for (int j = 0; j < LP; j++) dmin[j] = dst[TID + 256*j];
    far = a.far[ci];
  }
  __shared__ unsigned long long red2[2][4];
  for (int i = a.it0; i < a.it1; i++){
    float cx = pts[far*3+0], cy = pts[far*3+1], cz = pts[far*3+2];
    if (TID == 0){ out[i*3+0]=cx; out[i*3+1]=cy; out[i*3+2]=cz; }
    float bm = -1.f; int bp = 0;
#pragma unroll
    for (int j = 0; j < LP; j++){
      float dx = __fsub_rn(px[j], cx);
      float dy = __fsub_rn(py[j], cy);
      float dz = __fsub_rn(pz[j], cz);
      float d  = __fadd_rn(__fadd_rn(__fmul_rn(dx,dx), __fmul_rn(dy,dy)), __fmul_rn(dz,dz));
      float dm = fminf(dmin[j], d);
      dmin[j] = dm;
      if (dm > bm){ bm = dm; bp = TID + 256*j; }
    }
    dpp_comb<0x111>(bm,bp); dpp_comb<0x112>(bm,bp); dpp_comb<0x114>(bm,bp);
    dpp_comb<0x118>(bm,bp); dpp_comb<0x142>(bm,bp); dpp_comb<0x143>(bm,bp);
    unsigned long long key =
      ((unsigned long long)(unsigned)__builtin_amdgcn_readlane(__float_as_int(bm), 63) << 32)
      | (unsigned)~(unsigned)__builtin_amdgcn_readlane(bp, 63);
    if ((TID & 63) == 63) red2[i&1][TID>>6] = key;
    __syncthreads();
    unsigned long long k0=red2[i&1][0], k1=red2[i&1][1], k2=red2[i&1][2], k3=red2[i&1][3];
    k0 = k0>k1?k0:k1; k2 = k2>k3?k2:k3; k0 = k0>k2?k0:k2;
    far = (int)~(unsigned)k0;
  }
  if (a.it1 < 512){
#pragma unroll
    for (int j = 0; j < LP; j++) dst[TID + 256*j] = dmin[j];
    if (TID == 0) a.far[ci] = far;
  }
}

// swizzled float offset into the 128x128 A tile (breaks 4-way bank conflict
// when 4 tn-groups read the same k4-chunk of different n-rows)
__device__ __forceinline__ int aswz(int n, int k){
  return (n << 7) + ((((k >> 2) ^ ((n >> 3) & 3)) << 2) | (k & 3));
}

// ---------------- small row-GEMM with optional BN(+relu) on input load -----
template<int C, int K, int FLP>
__global__ void __launch_bounds__(256) rowgemm_kernel(const float* __restrict__ in,
    const float* __restrict__ w, const float* __restrict__ bias, const float2* __restrict__ st2,
    float* __restrict__ out, int rows_per_g, FpsArgs fa)
{
  int bid = blockIdx.x;
  if constexpr (FLP > 0){
    if (bid < fa.nc){ fps_body<FLP>(fa, bid); return; }
    bid -= fa.nc;
  }
  constexpr int RPB = 256 / C;
  __shared__ float lin[RPB * K];
  size_t row0 = (size_t)bid * RPB;
  int g = (int)(row0 / rows_per_g);
  for (int i = TID; i < RPB*K; i += 256){
    float v = in[row0*(size_t)K + i];
    if (st2){ float2 s = st2[(size_t)g*K + (i % K)]; v = fmaxf((v - s.x)*s.y, 0.f); }
    lin[i] = v;
  }
  __syncthreads();
  int r = TID / C, c = TID % C;
  float acc = bias[(size_t)g*C + c];
  const float* wg = w + (size_t)g*K*C + c;
#pragma unroll
  for (int k = 0; k < K; k++) acc = fmaf(lin[r*K + k], wg[(size_t)k*C], acc);
  out[(row0 + r)*C + c] = acc;
}

// ---------------- 1024-wide GEMM (K=128) for pointnet L3 (fused max+stats)
template<int FLP>
__global__ void __launch_bounds__(256) big1024_kernel(const float* __restrict__ in,
    const float* __restrict__ w, const float* __restrict__ bias, const float2* __restrict__ st2,
    float* __restrict__ ps, float* __restrict__ pq,
    unsigned* __restrict__ maxenc, int rows_per_g, FpsArgs fa)
{
  int bid = blockIdx.x;
  if constexpr (FLP > 0){
    if (bid < fa.nc){ fps_body<FLP>(fa, bid); return; }
    bid -= fa.nc;
  }
  int rb = bid >> 1, ch = bid & 1;
  __shared__ float lin[32 * 128];
  size_t row0 = (size_t)rb * 32;
  int g = (int)(row0 / rows_per_g);
  for (int i = TID; i < 32*128; i += 256){
    float v = in[row0*128 + i];
    if (st2){ float2 s = st2[(size_t)g*128 + (i & 127)]; v = fmaxf((v - s.x)*s.y, 0.f); }
    lin[i] = v;
  }
  __syncthreads();
  int c0 = ch*512 + TID, c1 = c0 + 256;
  float a0[32], a1[32];
  float b0 = bias[(size_t)g*1024 + c0], b1 = bias[(size_t)g*1024 + c1];
#pragma unroll
  for (int r = 0; r < 32; r++){ a0[r] = b0; a1[r] = b1; }
  const float* wg = w + (size_t)g*128*1024;
  for (int k = 0; k < 128; k++){
    float w0 = wg[(size_t)k*1024 + c0];
    float w1 = wg[(size_t)k*1024 + c1];
#pragma unroll
    for (int r = 0; r < 32; r++){
      float lv = lin[r*128 + k];
      a0[r] = fmaf(lv, w0, a0[r]);
      a1[r] = fmaf(lv, w1, a1[r]);
    }
  }
  int b = (int)(row0 / 2048);
  float s0=0.f,q0=0.f,m0=-1e38f,s1=0.f,q1=0.f,m1=-1e38f;
#pragma unroll
  for (int r = 0; r < 32; r++){
    s0 += a0[r]; q0 = fmaf(a0[r],a0[r],q0); m0 = fmaxf(m0, a0[r]);
    s1 += a1[r]; q1 = fmaf(a1[r],a1[r],q1); m1 = fmaxf(m1, a1[r]);
  }
  ps[(size_t)rb*1024 + c0] = s0; pq[(size_t)rb*1024 + c0] = q0;
  ps[(size_t)rb*1024 + c1] = s1; pq[(size_t)rb*1024 + c1] = q1;
  atomicMax(&maxenc[(size_t)b*1024 + c0], fenc(m0));
  atomicMax(&maxenc[(size_t)b*1024 + c1], fenc(m1));
}

// ---------------- per-branch skinny GEMM, K-split partials, input BN -------
template<int FLP>
__global__ void __launch_bounds__(256) mapgemm_kernel(const float* __restrict__ in, int in_gstride,
    const float* __restrict__ w, const float* __restrict__ bias, const float2* __restrict__ st2,
    float* __restrict__ out, int K, int J, int JB, int NS, FpsArgs fa)
{
  int bid = blockIdx.x;
  if constexpr (FLP > 0){
    if (bid < fa.nc){ fps_body<FLP>(fa, bid); return; }
    bid -= fa.nc;
  }
  int kc = bid / (JB*16);
  int g  = (bid / JB) % 16;
  int jb = bid % JB;
  int j  = jb*256 + TID;
  bool jv = j < J;
  int jc = jv ? j : 0;
  int kchunk = K / NS;
  int k0 = kc * kchunk;
  __shared__ float lin[16 * 128];
  const float* ing = in + (size_t)g * in_gstride;
  float acc[16];
  float bv = (NS == 1 && jv) ? bias[(size_t)g*J + jc] : 0.f;
#pragma unroll
  for (int b = 0; b < 16; b++) acc[b] = bv;
  for (int kt = k0; kt < k0 + kchunk; kt += 128){
    __syncthreads();
    for (int i = TID; i < 2048; i += 256){
      int b = i >> 7, k = i & 127;
      float v = ing[(size_t)b*K + kt + k];
      if (st2){ float2 s = st2[(size_t)g*K + kt + k]; v = fmaxf((v - s.x)*s.y, 0.f); }
      lin[i] = v;
    }
    __syncthreads();
    const float* wg = w + ((size_t)g*K + kt)*J + jc;
    for (int k = 0; k < 128; k++){
      float wv = wg[(size_t)k*J];
#pragma unroll
      for (int b = 0; b < 16; b++) acc[b] = fmaf(lin[b*128 + k], wv, acc[b]);
    }
  }
  if (jv){
    if (NS == 1){
      for (int b = 0; b < 16; b++) out[((size_t)g*16 + b)*J + j] = acc[b];
    } else {
      for (int b = 0; b < 16; b++) out[(((size_t)kc*16 + g)*16 + b)*J + j] = acc[b];
    }
  }
}

// sum K-split partials + bias, write tensor, compute BN stats over B=16 -----
__global__ void __launch_bounds__(256) redstats_kernel(const float* __restrict__ part,
    const float* __restrict__ bias, float* __restrict__ out, float2* __restrict__ st2,
    int J, int NS)
{
  int t = blockIdx.x*256 + TID;   // over G*J
  int g = t / J, j = t % J;
  float bv = bias[t];
  float s = 0.f, q = 0.f;
  for (int b = 0; b < 16; b++){
    float v = bv;
    for (int c = 0; c < NS; c++) v += part[(((size_t)c*16 + g)*16 + b)*J + j];
    out[((size_t)g*16 + b)*J + j] = v;
    s += v; q = fmaf(v, v, q);
  }
  float mean = s * (1.f/16.f);
  float var  = q * (1.f/16.f) - mean*mean;
  st2[t] = make_float2(mean, rsqrtf(fmaxf(var, 0.f) + EPSf));
}

// chunked coalesced BN partial sums (deterministic; no atomics) -------------
__global__ void __launch_bounds__(256) statsacc_kernel(const float* __restrict__ in,
    float* __restrict__ part, int C, size_t chunk)
{
  size_t base = (size_t)blockIdx.x * chunk;
  int c = TID % C;
  float s = 0.f, q = 0.f;
  for (size_t idx = base + TID; idx < base + chunk; idx += 256){
    float v = in[idx]; s += v; q = fmaf(v, v, q);
  }
  __shared__ float ls[256], lq[256];
  ls[TID] = s; lq[TID] = q; __syncthreads();
  if (TID < C){
    for (int t = TID + C; t < 256; t += C){ s += ls[t]; q += lq[t]; }
    part[((size_t)blockIdx.x*C + c)*2]   = s;
    part[((size_t)blockIdx.x*C + c)*2+1] = q;
  }
}

__global__ void statsfin_kernel(const float* __restrict__ part, float2* __restrict__ st2,
    int C, int G, float invR)
{
  int slot = blockIdx.x*256 + TID;
  if (slot >= G*C) return;
  int g = slot / C, c = slot % C;
  int bpg = 256 / G;
  float s = 0.f, q = 0.f;
  for (int b = 0; b < bpg; b++){
    size_t p = ((size_t)(g*bpg + b)*C + c)*2;
    s += part[p]; q += part[p+1];
  }
  float mean = s*invR;
  float var  = q*invR - mean*mean;
  st2[slot] = make_float2(mean, rsqrtf(fmaxf(var, 0.f) + EPSf));
}

// PointNet L3: reduce per-rowblock partials -> per-channel (mean,rstd) ------
__global__ void pnfin_kernel(const float* __restrict__ ps, const float* __restrict__ pq,
                             float2* __restrict__ st)
{
  int c = blockIdx.x*256 + TID;   // 1024
  float s = 0.f, q = 0.f;
  for (int rb = 0; rb < 1024; rb++){ s += ps[rb*1024 + c]; q += pq[rb*1024 + c]; }
  float mean = s * (1.f/32768.f);
  float var  = q * (1.f/32768.f) - mean*mean;
  st[c] = make_float2(mean, rsqrtf(fmaxf(var, 0.f) + EPSf));
}

__global__ void feat_kernel(const unsigned* __restrict__ me, const float2* __restrict__ st,
                            float* __restrict__ feat)
{
  int t = blockIdx.x*256 + TID;   // 16384
  int c = t & 1023;
  float2 s = st[c];
  feat[t] = (fdec(me[t]) - s.x) * s.y;
}

// ---------------- fused c3-GEMM + softmax(n) + y=w.xb + c4 ----------------
// One block per (gb, e-slab of 128). A = relu(BN(c2o tile)) in swizzled LDS;
// W streamed from global (L2-resident slab); h kept in regs -> LDS (reuses A);
// softmax + PV with 2 lanes per e-column. c3b skipped (softmax-invariant).
template<int FLP>
__global__ void __launch_bounds__(256) fused_kernel(const float* __restrict__ c2o,
    const float2* __restrict__ st2, const float* __restrict__ c3w,
    const float* __restrict__ xb, const float* __restrict__ c4w, const float* __restrict__ c4b,
    float* __restrict__ out_pts, float* __restrict__ out_x1, FpsArgs fa)
{
  int bid = blockIdx.x;
  if constexpr (FLP > 0){
    if (bid < fa.nc){ fps_body<FLP>(fa, bid); return; }
    bid -= fa.nc;
  }
  int gb = bid >> 3, eb = bid & 7;
  int g = gb >> 4, b = gb & 15;
  __shared__ float As[16384];   // A (swizzled) during GEMM; h afterwards
  __shared__ float xbl[4096];
  {
    const float* src = c2o + (size_t)gb*16384;
    for (int i = TID; i < 16384; i += 256){
      int n = i >> 7, k = i & 127;
      float2 s = st2[(size_t)g*128 + k];
      As[aswz(n,k)] = fmaxf((src[i] - s.x)*s.y, 0.f);
    }
    for (int i = TID; i < 4096; i += 256) xbl[i] = xb[(size_t)gb*4096 + i];
  }
  __syncthreads();

  int tn = TID >> 4, te = TID & 15;
  int n0 = tn*8, e0 = te*8;
  const float* wgp = c3w + ((size_t)g << 17) + eb*128 + e0;
  float h[8][8];
#pragma unroll
  for (int i = 0; i < 8; i++)
#pragma unroll
    for (int j = 0; j < 8; j++) h[i][j] = 0.f;

  for (int k4 = 0; k4 < 128; k4 += 4){
    float4 wa[4], wb[4], a[8];
#pragma unroll
    for (int kk = 0; kk < 4; kk++){
      wa[kk] = *(const float4*)(wgp + (size_t)(k4+kk)*1024);
      wb[kk] = *(const float4*)(wgp + (size_t)(k4+kk)*1024 + 4);
    }
#pragma unroll
    for (int i = 0; i < 8; i++) a[i] = *(const float4*)&As[aswz(n0+i, k4)];
#pragma unroll
    for (int kk = 0; kk < 4; kk++){
#pragma unroll
      for (int i = 0; i < 8; i++){
        float av = (&a[i].x)[kk];
        const float* w0 = &wa[kk].x;
        const float* w1 = &wb[kk].x;
#pragma unroll
        for (int j = 0; j < 4; j++){
          h[i][j]   = fmaf(av, w0[j], h[i][j]);
          h[i][j+4] = fmaf(av, w1[j], h[i][j+4]);
        }
      }
    }
  }
  __syncthreads();              // all GEMM reads of As done
#pragma unroll
  for (int i = 0; i < 8; i++){
#pragma unroll
    for (int j4 = 0; j4 < 8; j4 += 4)
      *(float4*)&As[(n0+i)*128 + e0 + j4] =
        make_float4(h[i][j4], h[i][j4+1], h[i][j4+2], h[i][j4+3]);
  }
  __syncthreads();

  // softmax over n + y = w.xb  (2 lanes per e-column, 64 n each)
  int e = TID >> 1, hh = TID & 1;
  int np0 = hh*64;
  float m = -1e38f;
  for (int j = 0; j < 64; j++) m = fmaxf(m, As[(np0+j)*128 + e]);
  m = fmaxf(m, __shfl_xor(m, 1));
  float s = 0.f;
  float4 y[8];
#pragma unroll
  for (int q = 0; q < 8; q++) y[q] = make_float4(0.f,0.f,0.f,0.f);
  for (int j = 0; j < 64; j++){
    float wv = __expf(As[(np0+j)*128 + e] - m);
    s += wv;
    const float4* xr = (const float4*)&xbl[(np0+j)*32];
#pragma unroll
    for (int q = 0; q < 8; q++){
      float4 xv = xr[q];
      y[q].x = fmaf(wv, xv.x, y[q].x);
      y[q].y = fmaf(wv, xv.y, y[q].y);
      y[q].z = fmaf(wv, xv.z, y[q].z);
      y[q].w = fmaf(wv, xv.w, y[q].w);
    }
  }
  s += __shfl_xor(s, 1);
#pragma unroll
  for (int q = 0; q < 8; q++){
    y[q].x += __shfl_xor(y[q].x, 1);
    y[q].y += __shfl_xor(y[q].y, 1);
    y[q].z += __shfl_xor(y[q].z, 1);
    y[q].w += __shfl_xor(y[q].w, 1);
  }
  if (hh == 0){
    const float* cw = c4w + g*96;
    float o0 = 0.f, o1 = 0.f, o2 = 0.f;
#pragma unroll
    for (int q = 0; q < 8; q++){
#pragma unroll
      for (int c2 = 0; c2 < 4; c2++){
        float yv = (&y[q].x)[c2];
        int k = q*4 + c2;
        o0 = fmaf(yv, cw[k*3+0], o0);
        o1 = fmaf(yv, cw[k*3+1], o1);
        o2 = fmaf(yv, cw[k*3+2], o2);
      }
    }
    float rs = 1.f / s;
    o0 = fmaf(rs, o0, c4b[g*3+0]);
    o1 = fmaf(rs, o1, c4b[g*3+1]);
    o2 = fmaf(rs, o2, c4b[g*3+2]);
    int eg = eb*128 + e;
    size_t po = ((size_t)gb*1024 + eg)*3;
    out_pts[po+0] = o0; out_pts[po+1] = o1; out_pts[po+2] = o2;
    if (out_x1){
      size_t xo = (((size_t)b*16 + g)*1024 + eg)*3;
      out_x1[xo+0] = o0; out_x1[xo+1] = o1; out_x1[xo+2] = o2;
    }
  }
}

// ---------------- x_2 = concat(fps1, x_partial) + d2 -----------------------
__global__ void combine_kernel(const float* __restrict__ fps1, const float* __restrict__ xpart,
                               const float* __restrict__ d2, float* __restrict__ x2)
{
  size_t i = (size_t)blockIdx.x*256 + TID;
  if (i >= (size_t)16*16*1024*3) return;
  int c = (int)(i % 3);
  size_t t = i / 3;
  int e = (int)(t % 1024);
  size_t gb = t / 1024;
  int g = (int)(gb >> 4), b = (int)(gb & 15);
  float base;
  if (e < 512) base = fps1[(gb*512 + e)*3 + c];
  else         base = xpart[((size_t)b*512 + (e - 512))*3 + c];
  x2[(((size_t)b*16384) + (size_t)g*1024 + e)*3 + c] = base + d2[i];
}

} // anon namespace

extern "C" void kernel_launch(void* const* d_in, const int* in_sizes, int n_in,
                              void* d_out, int out_size, void* d_ws, size_t ws_size,
                              hipStream_t stream)
{
  (void)in_sizes; (void)n_in; (void)out_size; (void)ws_size;
  const float* x    = (const float*)d_in[0];
  const float* pnw1 = (const float*)d_in[1];
  const float* pnb1 = (const float*)d_in[2];
  const float* pnw2 = (const float*)d_in[3];
  const float* pnb2 = (const float*)d_in[4];
  const float* pnw3 = (const float*)d_in[5];
  const float* pnb3 = (const float*)d_in[6];
  const float* mpw[4] = {(const float*)d_in[7],(const float*)d_in[9],(const float*)d_in[11],(const float*)d_in[13]};
  const float* mpb[4] = {(const float*)d_in[8],(const float*)d_in[10],(const float*)d_in[12],(const float*)d_in[14]};

  float* ws = (float*)d_ws;
  size_t o = 0;
  auto alloc = [&](size_t n){ float* p = ws + o; o += n; return p; };
  float* x_partial = alloc(24576);
  float* feat      = alloc(16384);
  float* mfeat     = alloc(32768);
  float2* st_pn1   = (float2*)alloc(128);
  float2* st_pn2   = (float2*)alloc(256);
  float2* st_pn3   = (float2*)alloc(2048);
  float2* st_c1    = (float2*)alloc(2048);
  float2* st_c2    = (float2*)alloc(4096);
  float2* st_map0  = (float2*)alloc(32768);
  float2* st_map1  = (float2*)alloc(32768);
  float2* st_map2  = (float2*)alloc(32768);
  float2* st_map3  = (float2*)alloc(4096);
  float* sa_part   = alloc(65536);
  float* pn_ps     = alloc(1048576);
  float* pn_pq     = alloc(1048576);
  unsigned* maxenc = (unsigned*)alloc(16384);
  float* mapA      = alloc(262144);
  float* mapB      = alloc(262144);
  float* mpart     = alloc(1048576);
  float* xb        = alloc(1048576);
  float* c1o       = alloc(2097152);
  float* c2o       = alloc(4194304);
  float* x1g       = alloc(786432);
  float* d2buf     = alloc(786432);
  float* fps1b     = alloc(393216);
  float* fpsA_dmin = alloc(32768);
  int*   fpsA_far  = (int*)alloc(16);
  float* fpsB_dmin = alloc(262144);
  int*   fpsB_far  = (int*)alloc(256);

  float* xout1 = (float*)d_out;
  float* xout2 = xout1 + 786432;

  hipMemsetAsync(maxenc, 0, 16384*sizeof(unsigned), stream);

  FpsArgs f0{};   // dummy for non-sidecar instantiations
  FpsArgs fa{x, x_partial, fpsA_dmin, fpsA_far, 0, 96, 16};

  // ---- PointNet (fps(x) rides as sidecar) ----
  rowgemm_kernel<64,3,8><<<8192+16, 256, 0, stream>>>(x, pnw1, pnb1, nullptr, c1o, 32768, fa);
  statsacc_kernel<<<256, 256, 0, stream>>>(c1o, sa_part, 64, 8192);
  statsfin_kernel<<<1, 256, 0, stream>>>(sa_part, st_pn1, 64, 1, 1.f/32768.f);
  fa.it0 = 96; fa.it1 = 256;
  rowgemm_kernel<128,64,8><<<16384+16, 256, 0, stream>>>(c1o, pnw2, pnb2, st_pn1, c2o, 32768, fa);
  statsacc_kernel<<<256, 256, 0, stream>>>(c2o, sa_part, 128, 16384);
  statsfin_kernel<<<1, 256, 0, stream>>>(sa_part, st_pn2, 128, 1, 1.f/32768.f);
  fa.it0 = 256; fa.it1 = 512;
  big1024_kernel<8><<<2048+16, 256, 0, stream>>>(c2o, pnw3, pnb3, st_pn2,
                                                 pn_ps, pn_pq, maxenc, 32768, fa);
  pnfin_kernel<<<4, 256, 0, stream>>>(pn_ps, pn_pq, st_pn3);
  feat_kernel<<<64, 256, 0, stream>>>(maxenc, st_pn3, feat);

  // ---- Mapping MLP (K-split x4, deterministic reduce + stats) ----
  mapgemm_kernel<0><<<256, 256, 0, stream>>>(feat, 0,     mpw[0], nullptr, nullptr, mpart, 1024, 1024, 4, 4, f0);
  redstats_kernel<<<64, 256, 0, stream>>>(mpart, mpb[0], mapA, st_map0, 1024, 4);
  mapgemm_kernel<0><<<256, 256, 0, stream>>>(mapA, 16384, mpw[1], nullptr, st_map0, mpart, 1024, 1024, 4, 4, f0);
  redstats_kernel<<<64, 256, 0, stream>>>(mpart, mpb[1], mapB, st_map1, 1024, 4);
  mapgemm_kernel<0><<<256, 256, 0, stream>>>(mapB, 16384, mpw[2], nullptr, st_map1, mpart, 1024, 1024, 4, 4, f0);
  redstats_kernel<<<64, 256, 0, stream>>>(mpart, mpb[2], mapA, st_map2, 1024, 4);
  mapgemm_kernel<0><<<64, 256, 0, stream>>>(mapA, 16384, mpw[3], nullptr, st_map2, mpart, 1024, 128, 1, 4, f0);
  redstats_kernel<<<8, 256, 0, stream>>>(mpart, mpb[3], mfeat, st_map3, 128, 4);

  // ---- Two AXform heads; fps(x1g) rides head 1 ----
  for (int p = 0; p < 2; p++){
    const float* fw  = (const float*)d_in[15 + p*10 + 0];
    const float* fb  = (const float*)d_in[15 + p*10 + 1];
    const float* c1w = (const float*)d_in[15 + p*10 + 2];
    const float* c1b = (const float*)d_in[15 + p*10 + 3];
    const float* c2w = (const float*)d_in[15 + p*10 + 4];
    const float* c2b = (const float*)d_in[15 + p*10 + 5];
    const float* c3w = (const float*)d_in[15 + p*10 + 6];
    const float* c4w = (const float*)d_in[15 + p*10 + 8];
    const float* c4b = (const float*)d_in[15 + p*10 + 9];

    if (p == 0){
      mapgemm_kernel<0><<<256, 256, 0, stream>>>(mfeat, 2048, fw, fb, st_map3, xb, 128, 4096, 16, 1, f0);
      rowgemm_kernel<64,32,0><<<8192, 256, 0, stream>>>(xb, c1w, c1b, nullptr, c1o, 2048, f0);
      statsacc_kernel<<<256, 256, 0, stream>>>(c1o, sa_part, 64, 8192);
      statsfin_kernel<<<4, 256, 0, stream>>>(sa_part, st_c1, 64, 16, 1.f/2048.f);
      rowgemm_kernel<128,64,0><<<16384, 256, 0, stream>>>(c1o, c2w, c2b, st_c1, c2o, 2048, f0);
      statsacc_kernel<<<256, 256, 0, stream>>>(c2o, sa_part, 128, 16384);
      statsfin_kernel<<<8, 256, 0, stream>>>(sa_part, st_c2, 128, 16, 1.f/2048.f);
      fused_kernel<0><<<2048, 256, 0, stream>>>(c2o, st_c2, c3w, xb, c4w, c4b, x1g, xout1, f0);
    } else {
      FpsArgs fb_{x1g, fps1b, fpsB_dmin, fpsB_far, 0, 64, 256};
      mapgemm_kernel<4><<<256+256, 256, 0, stream>>>(mfeat, 2048, fw, fb, st_map3, xb, 128, 4096, 16, 1, fb_);
      fb_.it0 = 64; fb_.it1 = 128;
      rowgemm_kernel<64,32,4><<<8192+256, 256, 0, stream>>>(xb, c1w, c1b, nullptr, c1o, 2048, fb_);
      statsacc_kernel<<<256, 256, 0, stream>>>(c1o, sa_part, 64, 8192);
      statsfin_kernel<<<4, 256, 0, stream>>>(sa_part, st_c1, 64, 16, 1.f/2048.f);
      fb_.it0 = 128; fb_.it1 = 256;
      rowgemm_kernel<128,64,4><<<16384+256, 256, 0, stream>>>(c1o, c2w, c2b, st_c1, c2o, 2048, fb_);
      statsacc_kernel<<<256, 256, 0, stream>>>(c2o, sa_part, 128, 16384);
      statsfin_kernel<<<8, 256, 0, stream>>>(sa_part, st_c2, 128, 16, 1.f/2048.f);
      fb_.it0 = 256; fb_.it1 = 512;
      fused_kernel<4><<<2048+256, 256, 0, stream>>>(c2o, st_c2, c3w, xb, c4w, c4b, d2buf, nullptr, fb_);
    }
  }

  combine_kernel<<<3072, 256, 0, stream>>>(fps1b, x_partial, d2buf, xout2);
}

// Round 5
// 1899.456 us; speedup vs baseline: 1.6993x; 1.1073x over previous
//
#include <hip/hip_runtime.h>
#include <math.h>

#define TID ((int)threadIdx.x)

namespace {
constexpr float EPSf = 1e-5f;

struct FpsArgs {
  const float* pts; float* out; float* dmin; int* far;
  int it0, it1, nc;
};

__device__ __forceinline__ unsigned fenc(float f){
  unsigned u = __float_as_uint(f);
  return (u & 0x80000000u) ? ~u : (u | 0x80000000u);
}
__device__ __forceinline__ float fdec(unsigned e){
  unsigned u = (e & 0x80000000u) ? (e & 0x7fffffffu) : ~e;
  return __uint_as_float(u);
}

// DPP combine step for (max dist, min index on tie) wave-64 reduction.
template<int CTRL>
__device__ __forceinline__ void dpp_comb(float& bm, int& bp){
  int om_i = __builtin_amdgcn_update_dpp(__float_as_int(bm), __float_as_int(bm), CTRL, 0xf, 0xf, false);
  int op   = __builtin_amdgcn_update_dpp(bp, bp, CTRL, 0xf, 0xf, false);
  float om = __int_as_float(om_i);
  if (om > bm || (om == bm && op < bp)){ bm = om; bp = op; }
}

// ---------------- FPS body (runs as sidecar blocks inside other kernels) ----
template<int LP>
__device__ void fps_body(const FpsArgs& a, int ci){
  const int NPTS = 256*LP;
  const float* pts = a.pts + (size_t)ci * NPTS * 3;
  float* out = a.out + (size_t)ci * 512 * 3;
  float* dst = a.dmin + (size_t)ci * NPTS;
  float px[LP], py[LP], pz[LP], dmin[LP];
#pragma unroll
  for (int j = 0; j < LP; j++){
    int p = TID + 256*j;
    px[j] = pts[p*3+0]; py[j] = pts[p*3+1]; pz[j] = pts[p*3+2];
  }
  int far;
  if (a.it0 == 0){
#pragma unroll
    for (int j = 0; j < LP; j++) dmin[j] = 1e10f;
    far = 0;
  } else {
#pragma unroll
    for (int j = 0; j < LP; j++) dmin[j] = dst[TID + 256*j];
    far = a.far[ci];
  }
  __shared__ unsigned long long red2[2][4];
  for (int i = a.it0; i < a.it1; i++){
    float cx = pts[far*3+0], cy = pts[far*3+1], cz = pts[far*3+2];
    if (TID == 0){ out[i*3+0]=cx; out[i*3+1]=cy; out[i*3+2]=cz; }
    float bm = -1.f; int bp = 0;
#pragma unroll
    for (int j = 0; j < LP; j++){
      float dx = __fsub_rn(px[j], cx);
      float dy = __fsub_rn(py[j], cy);
      float dz = __fsub_rn(pz[j], cz);
      float d  = __fadd_rn(__fadd_rn(__fmul_rn(dx,dx), __fmul_rn(dy,dy)), __fmul_rn(dz,dz));
      float dm = fminf(dmin[j], d);
      dmin[j] = dm;
      if (dm > bm){ bm = dm; bp = TID + 256*j; }
    }
    dpp_comb<0x111>(bm,bp); dpp_comb<0x112>(bm,bp); dpp_comb<0x114>(bm,bp);
    dpp_comb<0x118>(bm,bp); dpp_comb<0x142>(bm,bp); dpp_comb<0x143>(bm,bp);
    unsigned long long key =
      ((unsigned long long)(unsigned)__builtin_amdgcn_readlane(__float_as_int(bm), 63) << 32)
      | (unsigned)~(unsigned)__builtin_amdgcn_readlane(bp, 63);
    if ((TID & 63) == 63) red2[i&1][TID>>6] = key;
    __syncthreads();
    unsigned long long k0=red2[i&1][0], k1=red2[i&1][1], k2=red2[i&1][2], k3=red2[i&1][3];
    k0 = k0>k1?k0:k1; k2 = k2>k3?k2:k3; k0 = k0>k2?k0:k2;
    far = (int)~(unsigned)k0;
  }
  if (a.it1 < 512){
#pragma unroll
    for (int j = 0; j < LP; j++) dst[TID + 256*j] = dmin[j];
    if (TID == 0) a.far[ci] = far;
  }
}

// swizzled offsets: A k-half tile [128n][64k]; P half [128n][64e]
__device__ __forceinline__ int aswz64(int n, int k){
  return (n << 6) + ((((k >> 2) ^ ((n >> 3) & 3)) << 2) | (k & 3));
}
__device__ __forceinline__ int pswz(int n, int e){
  return (n << 6) + (e ^ (((n >> 3) & 3) << 3));
}

// ---------------- small row-GEMM with optional BN(+relu) on input load -----
template<int C, int K, int FLP>
__global__ void __launch_bounds__(256) rowgemm_kernel(const float* __restrict__ in,
    const float* __restrict__ w, const float* __restrict__ bias, const float2* __restrict__ st2,
    float* __restrict__ out, int rows_per_g, FpsArgs fa)
{
  int bid = blockIdx.x;
  if constexpr (FLP > 0){
    if (bid < fa.nc){ fps_body<FLP>(fa, bid); return; }
    bid -= fa.nc;
  }
  constexpr int RPB = 256 / C;
  __shared__ float lin[RPB * K];
  size_t row0 = (size_t)bid * RPB;
  int g = (int)(row0 / rows_per_g);
  for (int i = TID; i < RPB*K; i += 256){
    float v = in[row0*(size_t)K + i];
    if (st2){ float2 s = st2[(size_t)g*K + (i % K)]; v = fmaxf((v - s.x)*s.y, 0.f); }
    lin[i] = v;
  }
  __syncthreads();
  int r = TID / C, c = TID % C;
  float acc = bias[(size_t)g*C + c];
  const float* wg = w + (size_t)g*K*C + c;
#pragma unroll
  for (int k = 0; k < K; k++) acc = fmaf(lin[r*K + k], wg[(size_t)k*C], acc);
  out[(row0 + r)*C + c] = acc;
}

// ---------------- 1024-wide GEMM (K=128) for pointnet L3 (fused max+stats)
template<int FLP>
__global__ void __launch_bounds__(256) big1024_kernel(const float* __restrict__ in,
    const float* __restrict__ w, const float* __restrict__ bias, const float2* __restrict__ st2,
    float* __restrict__ ps, float* __restrict__ pq,
    unsigned* __restrict__ maxenc, int rows_per_g, FpsArgs fa)
{
  int bid = blockIdx.x;
  if constexpr (FLP > 0){
    if (bid < fa.nc){ fps_body<FLP>(fa, bid); return; }
    bid -= fa.nc;
  }
  int rb = bid >> 1, ch = bid & 1;
  __shared__ float lin[32 * 128];
  size_t row0 = (size_t)rb * 32;
  int g = (int)(row0 / rows_per_g);
  for (int i = TID; i < 32*128; i += 256){
    float v = in[row0*128 + i];
    if (st2){ float2 s = st2[(size_t)g*128 + (i & 127)]; v = fmaxf((v - s.x)*s.y, 0.f); }
    lin[i] = v;
  }
  __syncthreads();
  int c0 = ch*512 + TID, c1 = c0 + 256;
  float a0[32], a1[32];
  float b0 = bias[(size_t)g*1024 + c0], b1 = bias[(size_t)g*1024 + c1];
#pragma unroll
  for (int r = 0; r < 32; r++){ a0[r] = b0; a1[r] = b1; }
  const float* wg = w + (size_t)g*128*1024;
  for (int k = 0; k < 128; k++){
    float w0 = wg[(size_t)k*1024 + c0];
    float w1 = wg[(size_t)k*1024 + c1];
#pragma unroll
    for (int r = 0; r < 32; r++){
      float lv = lin[r*128 + k];
      a0[r] = fmaf(lv, w0, a0[r]);
      a1[r] = fmaf(lv, w1, a1[r]);
    }
  }
  int b = (int)(row0 / 2048);
  float s0=0.f,q0=0.f,m0=-1e38f,s1=0.f,q1=0.f,m1=-1e38f;
#pragma unroll
  for (int r = 0; r < 32; r++){
    s0 += a0[r]; q0 = fmaf(a0[r],a0[r],q0); m0 = fmaxf(m0, a0[r]);
    s1 += a1[r]; q1 = fmaf(a1[r],a1[r],q1); m1 = fmaxf(m1, a1[r]);
  }
  ps[(size_t)rb*1024 + c0] = s0; pq[(size_t)rb*1024 + c0] = q0;
  ps[(size_t)rb*1024 + c1] = s1; pq[(size_t)rb*1024 + c1] = q1;
  atomicMax(&maxenc[(size_t)b*1024 + c0], fenc(m0));
  atomicMax(&maxenc[(size_t)b*1024 + c1], fenc(m1));
}

// ---------------- per-branch skinny GEMM, K-split partials, input BN -------
template<int FLP>
__global__ void __launch_bounds__(256) mapgemm_kernel(const float* __restrict__ in, int in_gstride,
    const float* __restrict__ w, const float* __restrict__ bias, const float2* __restrict__ st2,
    float* __restrict__ out, int K, int J, int JB, int NS, FpsArgs fa)
{
  int bid = blockIdx.x;
  if constexpr (FLP > 0){
    if (bid < fa.nc){ fps_body<FLP>(fa, bid); return; }
    bid -= fa.nc;
  }
  int kc = bid / (JB*16);
  int g  = (bid / JB) % 16;
  int jb = bid % JB;
  int j  = jb*256 + TID;
  bool jv = j < J;
  int jc = jv ? j : 0;
  int kchunk = K / NS;
  int k0 = kc * kchunk;
  __shared__ float lin[16 * 128];
  const float* ing = in + (size_t)g * in_gstride;
  float acc[16];
  float bv = (NS == 1 && jv) ? bias[(size_t)g*J + jc] : 0.f;
#pragma unroll
  for (int b = 0; b < 16; b++) acc[b] = bv;
  for (int kt = k0; kt < k0 + kchunk; kt += 128){
    __syncthreads();
    for (int i = TID; i < 2048; i += 256){
      int b = i >> 7, k = i & 127;
      float v = ing[(size_t)b*K + kt + k];
      if (st2){ float2 s = st2[(size_t)g*K + kt + k]; v = fmaxf((v - s.x)*s.y, 0.f); }
      lin[i] = v;
    }
    __syncthreads();
    const float* wg = w + ((size_t)g*K + kt)*J + jc;
    for (int k = 0; k < 128; k++){
      float wv = wg[(size_t)k*J];
#pragma unroll
      for (int b = 0; b < 16; b++) acc[b] = fmaf(lin[b*128 + k], wv, acc[b]);
    }
  }
  if (jv){
    if (NS == 1){
      for (int b = 0; b < 16; b++) out[((size_t)g*16 + b)*J + j] = acc[b];
    } else {
      for (int b = 0; b < 16; b++) out[(((size_t)kc*16 + g)*16 + b)*J + j] = acc[b];
    }
  }
}

// sum K-split partials + bias, write tensor, compute BN stats over B=16 -----
__global__ void __launch_bounds__(256) redstats_kernel(const float* __restrict__ part,
    const float* __restrict__ bias, float* __restrict__ out, float2* __restrict__ st2,
    int J, int NS)
{
  int t = blockIdx.x*256 + TID;   // over G*J
  int g = t / J, j = t % J;
  float bv = bias[t];
  float s = 0.f, q = 0.f;
  for (int b = 0; b < 16; b++){
    float v = bv;
    for (int c = 0; c < NS; c++) v += part[(((size_t)c*16 + g)*16 + b)*J + j];
    out[((size_t)g*16 + b)*J + j] = v;
    s += v; q = fmaf(v, v, q);
  }
  float mean = s * (1.f/16.f);
  float var  = q * (1.f/16.f) - mean*mean;
  st2[t] = make_float2(mean, rsqrtf(fmaxf(var, 0.f) + EPSf));
}

// chunked coalesced BN partial sums (deterministic; no atomics) -------------
__global__ void __launch_bounds__(256) statsacc_kernel(const float* __restrict__ in,
    float* __restrict__ part, int C, size_t chunk)
{
  size_t base = (size_t)blockIdx.x * chunk;
  int c = TID % C;
  float s = 0.f, q = 0.f;
  for (size_t idx = base + TID; idx < base + chunk; idx += 256){
    float v = in[idx]; s += v; q = fmaf(v, v, q);
  }
  __shared__ float ls[256], lq[256];
  ls[TID] = s; lq[TID] = q; __syncthreads();
  if (TID < C){
    for (int t = TID + C; t < 256; t += C){ s += ls[t]; q += lq[t]; }
    part[((size_t)blockIdx.x*C + c)*2]   = s;
    part[((size_t)blockIdx.x*C + c)*2+1] = q;
  }
}

__global__ void statsfin_kernel(const float* __restrict__ part, float2* __restrict__ st2,
    int C, int G, float invR)
{
  int slot = blockIdx.x*256 + TID;
  if (slot >= G*C) return;
  int g = slot / C, c = slot % C;
  int bpg = 256 / G;
  float s = 0.f, q = 0.f;
  for (int b = 0; b < bpg; b++){
    size_t p = ((size_t)(g*bpg + b)*C + c)*2;
    s += part[p]; q += part[p+1];
  }
  float mean = s*invR;
  float var  = q*invR - mean*mean;
  st2[slot] = make_float2(mean, rsqrtf(fmaxf(var, 0.f) + EPSf));
}

// PointNet L3: reduce per-rowblock partials -> per-channel (mean,rstd) ------
__global__ void pnfin_kernel(const float* __restrict__ ps, const float* __restrict__ pq,
                             float2* __restrict__ st)
{
  int c = blockIdx.x*256 + TID;   // 1024
  float s = 0.f, q = 0.f;
  for (int rb = 0; rb < 1024; rb++){ s += ps[rb*1024 + c]; q += pq[rb*1024 + c]; }
  float mean = s * (1.f/32768.f);
  float var  = q * (1.f/32768.f) - mean*mean;
  st[c] = make_float2(mean, rsqrtf(fmaxf(var, 0.f) + EPSf));
}

__global__ void feat_kernel(const unsigned* __restrict__ me, const float2* __restrict__ st,
                            float* __restrict__ feat)
{
  int t = blockIdx.x*256 + TID;   // 16384
  int c = t & 1023;
  float2 s = st[c];
  feat[t] = (fdec(me[t]) - s.x) * s.y;
}

// ---------------- fused c3-GEMM + softmax(n) + y=w.xb + c4 ----------------
// One block per (gb, e-slab of 128). A staged in 2 k-halves (32KB buffer,
// swizzled); h accumulated fully in regs (8n x 8e per thread); the same
// 32KB buffer then holds P in 2 e-half passes for softmax+PV.
// LDS ~48KB -> 3 blocks/CU; launch_bounds forces VGPR<=128 (4 waves/SIMD).
template<int FLP>
__global__ void __launch_bounds__(256, 4) fused_kernel(const float* __restrict__ c2o,
    const float2* __restrict__ st2, const float* __restrict__ c3w,
    const float* __restrict__ xb, const float* __restrict__ c4w, const float* __restrict__ c4b,
    float* __restrict__ out_pts, float* __restrict__ out_x1, FpsArgs fa)
{
  int bid = blockIdx.x;
  if constexpr (FLP > 0){
    if (bid < fa.nc){ fps_body<FLP>(fa, bid); return; }
    bid -= fa.nc;
  }
  int gb = bid >> 3, eb = bid & 7;
  int g = gb >> 4, b = gb & 15;
  __shared__ float As[8192];    // A k-half (swizzled), then P e-half
  __shared__ float xbl[4096];
  for (int i = TID; i < 4096; i += 256) xbl[i] = xb[(size_t)gb*4096 + i];

  int tn = TID >> 4, te = TID & 15;
  int n0 = tn*8, e0 = te*8;
  const float* wgp = c3w + ((size_t)g << 17) + eb*128 + e0;
  const float* src = c2o + (size_t)gb*16384;
  float h[8][8];
#pragma unroll
  for (int i = 0; i < 8; i++)
#pragma unroll
    for (int j = 0; j < 8; j++) h[i][j] = 0.f;

  for (int kh = 0; kh < 2; kh++){
    __syncthreads();            // previous pass readers done / xbl ready
    for (int i = TID; i < 8192; i += 256){
      int n = i >> 6, k = i & 63;
      int kg = kh*64 + k;
      float2 s = st2[(size_t)g*128 + kg];
      As[aswz64(n,k)] = fmaxf((src[n*128 + kg] - s.x)*s.y, 0.f);
    }
    __syncthreads();
    for (int k4 = 0; k4 < 64; k4 += 4){
      float4 a[8];
#pragma unroll
      for (int i = 0; i < 8; i++) a[i] = *(const float4*)&As[aswz64(n0+i, k4)];
#pragma unroll
      for (int kk = 0; kk < 4; kk++){
        float4 wa = *(const float4*)(wgp + (size_t)(kh*64 + k4 + kk)*1024);
        float4 wb = *(const float4*)(wgp + (size_t)(kh*64 + k4 + kk)*1024 + 4);
#pragma unroll
        for (int i = 0; i < 8; i++){
          float av = (&a[i].x)[kk];
          h[i][0] = fmaf(av, wa.x, h[i][0]);
          h[i][1] = fmaf(av, wa.y, h[i][1]);
          h[i][2] = fmaf(av, wa.z, h[i][2]);
          h[i][3] = fmaf(av, wa.w, h[i][3]);
          h[i][4] = fmaf(av, wb.x, h[i][4]);
          h[i][5] = fmaf(av, wb.y, h[i][5]);
          h[i][6] = fmaf(av, wb.z, h[i][6]);
          h[i][7] = fmaf(av, wb.w, h[i][7]);
        }
      }
    }
  }

  // two e-half passes: P = h-half in As, softmax over n, PV, c4 epilogue
  for (int p = 0; p < 2; p++){
    __syncthreads();            // GEMM / previous-pass reads of As done
    if ((te >> 3) == p){
      int el0 = (te & 7) * 8;
#pragma unroll
      for (int i = 0; i < 8; i++){
#pragma unroll
        for (int j4 = 0; j4 < 8; j4 += 4)
          *(float4*)&As[pswz(n0+i, el0+j4)] =
            make_float4(h[i][j4], h[i][j4+1], h[i][j4+2], h[i][j4+3]);
      }
    }
    __syncthreads();
    if (TID < 128){
      int el = TID >> 1, hh = TID & 1;
      float m = -1e38f;
      for (int jj = 0; jj < 64; jj++){
        int n = hh*64 + jj;
        m = fmaxf(m, As[pswz(n, el)]);
      }
      m = fmaxf(m, __shfl_xor(m, 1));
      float s = 0.f;
      float4 y[8];
#pragma unroll
      for (int q = 0; q < 8; q++) y[q] = make_float4(0.f,0.f,0.f,0.f);
      for (int jj = 0; jj < 64; jj++){
        int n = hh*64 + jj;
        float wv = __expf(As[pswz(n, el)] - m);
        s += wv;
        const float4* xr = (const float4*)&xbl[n*32];
#pragma unroll
        for (int q = 0; q < 8; q++){
          float4 xv = xr[q];
          y[q].x = fmaf(wv, xv.x, y[q].x);
          y[q].y = fmaf(wv, xv.y, y[q].y);
          y[q].z = fmaf(wv, xv.z, y[q].z);
          y[q].w = fmaf(wv, xv.w, y[q].w);
        }
      }
      s += __shfl_xor(s, 1);
#pragma unroll
      for (int q = 0; q < 8; q++){
        y[q].x += __shfl_xor(y[q].x, 1);
        y[q].y += __shfl_xor(y[q].y, 1);
        y[q].z += __shfl_xor(y[q].z, 1);
        y[q].w += __shfl_xor(y[q].w, 1);
      }
      if (hh == 0){
        const float* cw = c4w + g*96;
        float o0 = 0.f, o1 = 0.f, o2 = 0.f;
#pragma unroll
        for (int q = 0; q < 8; q++){
#pragma unroll
          for (int c2 = 0; c2 < 4; c2++){
            float yv = (&y[q].x)[c2];
            int k = q*4 + c2;
            o0 = fmaf(yv, cw[k*3+0], o0);
            o1 = fmaf(yv, cw[k*3+1], o1);
            o2 = fmaf(yv, cw[k*3+2], o2);
          }
        }
        float rs = 1.f / s;
        o0 = fmaf(rs, o0, c4b[g*3+0]);
        o1 = fmaf(rs, o1, c4b[g*3+1]);
        o2 = fmaf(rs, o2, c4b[g*3+2]);
        int eg = eb*128 + p*64 + el;
        size_t po = ((size_t)gb*1024 + eg)*3;
        out_pts[po+0] = o0; out_pts[po+1] = o1; out_pts[po+2] = o2;
        if (out_x1){
          size_t xo = (((size_t)b*16 + g)*1024 + eg)*3;
          out_x1[xo+0] = o0; out_x1[xo+1] = o1; out_x1[xo+2] = o2;
        }
      }
    }
  }
}

// ---------------- x_2 = concat(fps1, x_partial) + d2 -----------------------
__global__ void combine_kernel(const float* __restrict__ fps1, const float* __restrict__ xpart,
                               const float* __restrict__ d2, float* __restrict__ x2)
{
  size_t i = (size_t)blockIdx.x*256 + TID;
  if (i >= (size_t)16*16*1024*3) return;
  int c = (int)(i % 3);
  size_t t = i / 3;
  int e = (int)(t % 1024);
  size_t gb = t / 1024;
  int g = (int)(gb >> 4), b = (int)(gb & 15);
  float base;
  if (e < 512) base = fps1[(gb*512 + e)*3 + c];
  else         base = xpart[((size_t)b*512 + (e - 512))*3 + c];
  x2[(((size_t)b*16384) + (size_t)g*1024 + e)*3 + c] = base + d2[i];
}

} // anon namespace

extern "C" void kernel_launch(void* const* d_in, const int* in_sizes, int n_in,
                              void* d_out, int out_size, void* d_ws, size_t ws_size,
                              hipStream_t stream)
{
  (void)in_sizes; (void)n_in; (void)out_size; (void)ws_size;
  const float* x    = (const float*)d_in[0];
  const float* pnw1 = (const float*)d_in[1];
  const float* pnb1 = (const float*)d_in[2];
  const float* pnw2 = (const float*)d_in[3];
  const float* pnb2 = (const float*)d_in[4];
  const float* pnw3 = (const float*)d_in[5];
  const float* pnb3 = (const float*)d_in[6];
  const float* mpw[4] = {(const float*)d_in[7],(const float*)d_in[9],(const float*)d_in[11],(const float*)d_in[13]};
  const float* mpb[4] = {(const float*)d_in[8],(const float*)d_in[10],(const float*)d_in[12],(const float*)d_in[14]};

  float* ws = (float*)d_ws;
  size_t o = 0;
  auto alloc = [&](size_t n){ float* p = ws + o; o += n; return p; };
  float* x_partial = alloc(24576);
  float* feat      = alloc(16384);
  float* mfeat     = alloc(32768);
  float2* st_pn1   = (float2*)alloc(128);
  float2* st_pn2   = (float2*)alloc(256);
  float2* st_pn3   = (float2*)alloc(2048);
  float2* st_c1    = (float2*)alloc(2048);
  float2* st_c2    = (float2*)alloc(4096);
  float2* st_map0  = (float2*)alloc(32768);
  float2* st_map1  = (float2*)alloc(32768);
  float2* st_map2  = (float2*)alloc(32768);
  float2* st_map3  = (float2*)alloc(4096);
  float* sa_part   = alloc(65536);
  float* pn_ps     = alloc(1048576);
  float* pn_pq     = alloc(1048576);
  unsigned* maxenc = (unsigned*)alloc(16384);
  float* mapA      = alloc(262144);
  float* mapB      = alloc(262144);
  float* mpart     = alloc(1048576);
  float* xb        = alloc(1048576);
  float* c1o       = alloc(2097152);
  float* c2o       = alloc(4194304);
  float* x1g       = alloc(786432);
  float* d2buf     = alloc(786432);
  float* fps1b     = alloc(393216);
  float* fpsA_dmin = alloc(32768);
  int*   fpsA_far  = (int*)alloc(16);
  float* fpsB_dmin = alloc(262144);
  int*   fpsB_far  = (int*)alloc(256);

  float* xout1 = (float*)d_out;
  float* xout2 = xout1 + 786432;

  hipMemsetAsync(maxenc, 0, 16384*sizeof(unsigned), stream);

  FpsArgs f0{};   // dummy for non-sidecar instantiations
  FpsArgs fa{x, x_partial, fpsA_dmin, fpsA_far, 0, 96, 16};

  // ---- PointNet (fps(x) rides as sidecar) ----
  rowgemm_kernel<64,3,8><<<8192+16, 256, 0, stream>>>(x, pnw1, pnb1, nullptr, c1o, 32768, fa);
  statsacc_kernel<<<256, 256, 0, stream>>>(c1o, sa_part, 64, 8192);
  statsfin_kernel<<<1, 256, 0, stream>>>(sa_part, st_pn1, 64, 1, 1.f/32768.f);
  fa.it0 = 96; fa.it1 = 256;
  rowgemm_kernel<128,64,8><<<16384+16, 256, 0, stream>>>(c1o, pnw2, pnb2, st_pn1, c2o, 32768, fa);
  statsacc_kernel<<<256, 256, 0, stream>>>(c2o, sa_part, 128, 16384);
  statsfin_kernel<<<1, 256, 0, stream>>>(sa_part, st_pn2, 128, 1, 1.f/32768.f);
  fa.it0 = 256; fa.it1 = 512;
  big1024_kernel<8><<<2048+16, 256, 0, stream>>>(c2o, pnw3, pnb3, st_pn2,
                                                 pn_ps, pn_pq, maxenc, 32768, fa);
  pnfin_kernel<<<4, 256, 0, stream>>>(pn_ps, pn_pq, st_pn3);
  feat_kernel<<<64, 256, 0, stream>>>(maxenc, st_pn3, feat);

  // ---- Mapping MLP (K-split x4, deterministic reduce + stats) ----
  mapgemm_kernel<0><<<256, 256, 0, stream>>>(feat, 0,     mpw[0], nullptr, nullptr, mpart, 1024, 1024, 4, 4, f0);
  redstats_kernel<<<64, 256, 0, stream>>>(mpart, mpb[0], mapA, st_map0, 1024, 4);
  mapgemm_kernel<0><<<256, 256, 0, stream>>>(mapA, 16384, mpw[1], nullptr, st_map0, mpart, 1024, 1024, 4, 4, f0);
  redstats_kernel<<<64, 256, 0, stream>>>(mpart, mpb[1], mapB, st_map1, 1024, 4);
  mapgemm_kernel<0><<<256, 256, 0, stream>>>(mapB, 16384, mpw[2], nullptr, st_map1, mpart, 1024, 1024, 4, 4, f0);
  redstats_kernel<<<64, 256, 0, stream>>>(mpart, mpb[2], mapA, st_map2, 1024, 4);
  mapgemm_kernel<0><<<64, 256, 0, stream>>>(mapA, 16384, mpw[3], nullptr, st_map2, mpart, 1024, 128, 1, 4, f0);
  redstats_kernel<<<8, 256, 0, stream>>>(mpart, mpb[3], mfeat, st_map3, 128, 4);

  // ---- Two AXform heads; fps(x1g) rides head 1 ----
  for (int p = 0; p < 2; p++){
    const float* fw  = (const float*)d_in[15 + p*10 + 0];
    const float* fb  = (const float*)d_in[15 + p*10 + 1];
    const float* c1w = (const float*)d_in[15 + p*10 + 2];
    const float* c1b = (const float*)d_in[15 + p*10 + 3];
    const float* c2w = (const float*)d_in[15 + p*10 + 4];
    const float* c2b = (const float*)d_in[15 + p*10 + 5];
    const float* c3w = (const float*)d_in[15 + p*10 + 6];
    const float* c4w = (const float*)d_in[15 + p*10 + 8];
    const float* c4b = (const float*)d_in[15 + p*10 + 9];

    if (p == 0){
      mapgemm_kernel<0><<<256, 256, 0, stream>>>(mfeat, 2048, fw, fb, st_map3, xb, 128, 4096, 16, 1, f0);
      rowgemm_kernel<64,32,0><<<8192, 256, 0, stream>>>(xb, c1w, c1b, nullptr, c1o, 2048, f0);
      statsacc_kernel<<<256, 256, 0, stream>>>(c1o, sa_part, 64, 8192);
      statsfin_kernel<<<4, 256, 0, stream>>>(sa_part, st_c1, 64, 16, 1.f/2048.f);
      rowgemm_kernel<128,64,0><<<16384, 256, 0, stream>>>(c1o, c2w, c2b, st_c1, c2o, 2048, f0);
      statsacc_kernel<<<256, 256, 0, stream>>>(c2o, sa_part, 128, 16384);
      statsfin_kernel<<<8, 256, 0, stream>>>(sa_part, st_c2, 128, 16, 1.f/2048.f);
      fused_kernel<0><<<2048, 256, 0, stream>>>(c2o, st_c2, c3w, xb, c4w, c4b, x1g, xout1, f0);
    } else {
      FpsArgs fb_{x1g, fps1b, fpsB_dmin, fpsB_far, 0, 64, 256};
      mapgemm_kernel<4><<<256+256, 256, 0, stream>>>(mfeat, 2048, fw, fb, st_map3, xb, 128, 4096, 16, 1, fb_);
      fb_.it0 = 64; fb_.it1 = 128;
      rowgemm_kernel<64,32,4><<<8192+256, 256, 0, stream>>>(xb, c1w, c1b, nullptr, c1o, 2048, fb_);
      statsacc_kernel<<<256, 256, 0, stream>>>(c1o, sa_part, 64, 8192);
      statsfin_kernel<<<4, 256, 0, stream>>>(sa_part, st_c1, 64, 16, 1.f/2048.f);
      fb_.it0 = 128; fb_.it1 = 256;
      rowgemm_kernel<128,64,4><<<16384+256, 256, 0, stream>>>(c1o, c2w, c2b, st_c1, c2o, 2048, fb_);
      statsacc_kernel<<<256, 256, 0, stream>>>(c2o, sa_part, 128, 16384);
      statsfin_kernel<<<8, 256, 0, stream>>>(sa_part, st_c2, 128, 16, 1.f/2048.f);
      fb_.it0 = 256; fb_.it1 = 512;
      fused_kernel<4><<<2048+256, 256, 0, stream>>>(c2o, st_c2, c3w, xb, c4w, c4b, d2buf, nullptr, fb_);
    }
  }

  combine_kernel<<<3072, 256, 0, stream>>>(fps1b, x_partial, d2buf, xout2);
}